// Round 10
// baseline (2302.302 us; speedup 1.0000x reference)
//
#include <hip/hip_runtime.h>
#include <math.h>

typedef __attribute__((ext_vector_type(8))) short bf16x8;
typedef __attribute__((ext_vector_type(4))) float f32x4;

__device__ inline ushort f2bf(float f) {
  unsigned u = __builtin_bit_cast(unsigned, f);
  unsigned r = (u + 0x7FFFu + ((u >> 16) & 1u)) >> 16;
  return (ushort)r;
}
__device__ inline float bf2f(ushort h) {
  return __builtin_bit_cast(float, (unsigned)h << 16);
}
__device__ inline void split2(float f, ushort& hi, ushort& lo) {
  hi = f2bf(f);
  lo = f2bf(f - bf2f(hi));
}

// ---------------- weight fusion: BT[c][r] = sum_t W_sub[i,t]*lnW[sub*dmid+t,c], r=sub*256+i
__global__ void fuse_w_kernel(const float* __restrict__ w0,
                              const float* __restrict__ w1,
                              const float* __restrict__ w2,
                              const float* __restrict__ lnW,
                              ushort* __restrict__ BTh, ushort* __restrict__ BTl,
                              int dmid, int dn) {
  int idx = blockIdx.x * blockDim.x + threadIdx.x;
  int total = 768 * dn;
  if (idx >= total) return;
  int r = idx / dn, c = idx - r * dn;
  int sub = r >> 8, i = r & 255;
  const float* W = (sub == 0) ? w0 : (sub == 1) ? w1 : w2;
  float acc = 0.f;
  for (int t = 0; t < dmid; ++t)
    acc += W[i * dmid + t] * lnW[(sub * dmid + t) * dn + c];
  ushort hi, lo; split2(acc, hi, lo);
  BTh[(size_t)c * 768 + r] = hi;
  BTl[(size_t)c * 768 + r] = lo;
}

// grid = dn blocks; 256 threads reduce 3*dmid terms for column c = blockIdx.x
__global__ __launch_bounds__(256)
void fuse_b_kernel(const float* __restrict__ b0,
                   const float* __restrict__ b1,
                   const float* __restrict__ b2,
                   const float* __restrict__ lnW,
                   const float* __restrict__ lnb,
                   float* __restrict__ biasf, int dmid, int dn) {
  int c = blockIdx.x;
  int t = threadIdx.x;
  float acc = 0.f;
  for (int k = t; k < 3 * dmid; k += 256) {
    int sub = k / dmid, w = k - sub * dmid;
    const float* bb = (sub == 0) ? b0 : (sub == 1) ? b1 : b2;
    acc += bb[w] * lnW[(size_t)k * dn + c];
  }
  for (int off = 32; off; off >>= 1) acc += __shfl_xor(acc, off);
  __shared__ float wsum[4];
  if ((t & 63) == 0) wsum[t >> 6] = acc;
  __syncthreads();
  if (t == 0) biasf[c] = lnb[c] + wsum[0] + wsum[1] + wsum[2] + wsum[3];
}

// ---------------- CSR build ----------------
__global__ void hist_kernel(const int* __restrict__ ei, int* cnt, int E) {
  int e = blockIdx.x * 256 + threadIdx.x;
  if (e < E) atomicAdd(&cnt[ei[E + e]], 1);
}

// single workgroup exclusive scan, wave-shuffle based
__global__ void scan_kernel(const int* cnt, int* offs, int* cur, int n) {
  __shared__ int wsum[16];
  __shared__ int running;
  int t = threadIdx.x;
  if (t == 0) running = 0;
  __syncthreads();
  for (int base = 0; base < n; base += 1024) {
    int i = base + t;
    int c = (i < n) ? cnt[i] : 0;
    int v = c;
#pragma unroll
    for (int off = 1; off < 64; off <<= 1) {
      int u = __shfl_up(v, off);
      if ((t & 63) >= off) v += u;
    }
    if ((t & 63) == 63) wsum[t >> 6] = v;
    __syncthreads();
    if (t < 16) {
      int s = wsum[t];
#pragma unroll
      for (int off = 1; off < 16; off <<= 1) {
        int u = __shfl_up(s, off, 16);
        if (t >= off) s += u;
      }
      wsum[t] = s;
    }
    __syncthreads();
    int wid6 = t >> 6;
    int waveoff = (wid6 == 0) ? 0 : wsum[wid6 - 1];
    int incl = v + waveoff;
    int r = running;
    if (i < n) { int ex = r + incl - c; offs[i] = ex; cur[i] = ex; }
    __syncthreads();
    if (t == 1023) running = r + incl;
    __syncthreads();
  }
  if (t == 0) offs[n] = running;
}

__global__ void fill_kernel(const int* __restrict__ ei, const float* __restrict__ ew,
                            int* cur, int2* __restrict__ csr, int E) {
  int e = blockIdx.x * 256 + threadIdx.x;
  if (e >= E) return;
  int dst = ei[E + e];
  int pos = atomicAdd(&cur[dst], 1);
  csr[pos] = make_int2(ei[e], __float_as_int(ew[e]));
}

// ---------------- x -> (hi,lo) bf16 split ----------------
__global__ void conv_split_kernel(const float* __restrict__ X,
                                  ushort* __restrict__ Xh, ushort* __restrict__ Xl,
                                  size_t n4) {
  size_t i = (size_t)blockIdx.x * 256 + threadIdx.x;
  if (i >= n4) return;
  float4 v = *(const float4*)(X + i * 4);
  ushort4 h, l;
  split2(v.x, h.x, l.x); split2(v.y, h.y, l.y);
  split2(v.z, h.z, l.z); split2(v.w, h.w, l.w);
  *(ushort4*)(Xh + i * 4) = h;
  *(ushort4*)(Xl + i * 4) = l;
}

// ---------------- aggregation (256-wide): one wave per dst row, bf16 gather ----------------
__global__ __launch_bounds__(256)
void agg_bf16_kernel(const int* __restrict__ offs, const int2* __restrict__ csr,
                     const ushort* __restrict__ Xh,
                     ushort* __restrict__ Zh, ushort* __restrict__ Zl, int Nn) {
  int wid = blockIdx.x * 4 + (threadIdx.x >> 6);
  if (wid >= Nn) return;
  int lane = threadIdx.x & 63;
  int beg = offs[wid], end = offs[wid + 1];
  float a0 = 0.f, a1 = 0.f, a2 = 0.f, a3 = 0.f;
  for (int i = beg; i < end; ++i) {
    int2 p = csr[i];
    float w = __int_as_float(p.y);
    ushort4 v = *(const ushort4*)(Xh + (size_t)p.x * 256 + lane * 4);
    a0 = fmaf(w, bf2f(v.x), a0);
    a1 = fmaf(w, bf2f(v.y), a1);
    a2 = fmaf(w, bf2f(v.z), a2);
    a3 = fmaf(w, bf2f(v.w), a3);
  }
  ushort4 h, l;
  split2(a0, h.x, l.x); split2(a1, h.y, l.y);
  split2(a2, h.z, l.z); split2(a3, h.w, l.w);
  *(ushort4*)(Zh + (size_t)wid * 256 + lane * 4) = h;
  *(ushort4*)(Zl + (size_t)wid * 256 + lane * 4) = l;
}

// ---------------- aggregation (64-wide): gather 128B slices of P[N,192] ----------------
__global__ __launch_bounds__(256)
void agg64_kernel(const int* __restrict__ offs, const int2* __restrict__ csr,
                  const ushort* __restrict__ P, int goff,
                  float* __restrict__ Z, int Nn) {
  int wid = blockIdx.x * 4 + (threadIdx.x >> 6);
  if (wid >= Nn) return;
  int lane = threadIdx.x & 63;
  int beg = offs[wid], end = offs[wid + 1];
  float acc = 0.f;
  for (int i = beg; i < end; ++i) {
    int2 p = csr[i];
    float w = __int_as_float(p.y);
    acc = fmaf(w, bf2f(P[(size_t)p.x * 192 + goff + lane]), acc);
  }
  Z[(size_t)wid * 64 + lane] = acc;
}

// ---------------- MFMA GEMM blocks 1-2: C = [A0|A1|A2](hi+lo) @ BT(hi+lo) + bias ----------------
// wave tile 32x64 (acc[2][4]); block = 2x2 waves covers 64x128; grid (ceil(M/64), dn/128)
__global__ __launch_bounds__(256)
void gemm_mfma32_kernel(const ushort* __restrict__ A0h, const ushort* __restrict__ A0l,
                        const ushort* __restrict__ A1h, const ushort* __restrict__ A1l,
                        const ushort* __restrict__ A2h, const ushort* __restrict__ A2l,
                        const ushort* __restrict__ BTh, const ushort* __restrict__ BTl,
                        const float* __restrict__ bias,
                        ushort* __restrict__ Chi, ushort* __restrict__ Clo,
                        int M, int dn) {
  int tid = threadIdx.x;
  int w = tid >> 6, lane = tid & 63;
  int wr = w >> 1, wc = w & 1;
  int m0 = blockIdx.x * 64 + wr * 32;
  int n0 = blockIdx.y * 128 + wc * 64;
  int r16 = lane & 15, kg = lane >> 4;
  const ushort* Ah[3] = {A0h, A1h, A2h};
  const ushort* Al[3] = {A0l, A1l, A2l};
  f32x4 acc[2][4] = {};
  const bf16x8 zf = {0, 0, 0, 0, 0, 0, 0, 0};

  for (int k0 = 0; k0 < 768; k0 += 32) {
    const ushort* ah = Ah[k0 >> 8];
    const ushort* al = Al[k0 >> 8];
    int kl = (k0 & 255) + kg * 8;
    bf16x8 afh[2], afl[2], bfh[4], bfl[4];
#pragma unroll
    for (int i = 0; i < 2; ++i) {
      int row = m0 + i * 16 + r16;
      if (row < M) {
        afh[i] = *(const bf16x8*)(ah + (size_t)row * 256 + kl);
        afl[i] = *(const bf16x8*)(al + (size_t)row * 256 + kl);
      } else { afh[i] = zf; afl[i] = zf; }
    }
#pragma unroll
    for (int j = 0; j < 4; ++j) {
      int n = n0 + j * 16 + r16;
      bfh[j] = *(const bf16x8*)(BTh + (size_t)n * 768 + k0 + kg * 8);
      bfl[j] = *(const bf16x8*)(BTl + (size_t)n * 768 + k0 + kg * 8);
    }
#pragma unroll
    for (int i = 0; i < 2; ++i)
#pragma unroll
      for (int j = 0; j < 4; ++j) {
        acc[i][j] = __builtin_amdgcn_mfma_f32_16x16x32_bf16(afh[i], bfh[j], acc[i][j], 0, 0, 0);
        acc[i][j] = __builtin_amdgcn_mfma_f32_16x16x32_bf16(afh[i], bfl[j], acc[i][j], 0, 0, 0);
        acc[i][j] = __builtin_amdgcn_mfma_f32_16x16x32_bf16(afl[i], bfh[j], acc[i][j], 0, 0, 0);
      }
  }
  int qbase = (lane >> 4) * 4;
  int ccol = lane & 15;
#pragma unroll
  for (int i = 0; i < 2; ++i) {
#pragma unroll
    for (int j = 0; j < 4; ++j) {
      int col = n0 + j * 16 + ccol;
      float bv = bias[col];
#pragma unroll
      for (int q = 0; q < 4; ++q) {
        int row = m0 + i * 16 + qbase + q;
        if (row < M) {
          float c = acc[i][j][q] + bv;
          ushort hi, lo; split2(c, hi, lo);
          Chi[(size_t)row * dn + col] = hi;
          Clo[(size_t)row * dn + col] = lo;
        }
      }
    }
  }
}

// ---------------- block-3 projection GEMM: P[:, j*64+c] = XA @ M_j, K=256, bf16 out, no bias
// wave tile 32x64; block = 4 waves stacked on M covers 128 rows; grid (ceil(M/128), 3)
__global__ __launch_bounds__(256)
void gemm_proj_kernel(const ushort* __restrict__ XAh, const ushort* __restrict__ XAl,
                      const ushort* __restrict__ BTh, const ushort* __restrict__ BTl,
                      ushort* __restrict__ P, int M) {
  int tid = threadIdx.x;
  int w = tid >> 6, lane = tid & 63;
  int m0 = blockIdx.x * 128 + w * 32;
  int chunk = blockIdx.y;           // 0..2 -> M0,M1,M2 (k-offset chunk*256 in BT[c][768])
  int r16 = lane & 15, kg = lane >> 4;
  f32x4 acc[2][4] = {};
  const bf16x8 zf = {0, 0, 0, 0, 0, 0, 0, 0};

  for (int k0 = 0; k0 < 256; k0 += 32) {
    int kl = k0 + kg * 8;
    bf16x8 afh[2], afl[2], bfh[4], bfl[4];
#pragma unroll
    for (int i = 0; i < 2; ++i) {
      int row = m0 + i * 16 + r16;
      if (row < M) {
        afh[i] = *(const bf16x8*)(XAh + (size_t)row * 256 + kl);
        afl[i] = *(const bf16x8*)(XAl + (size_t)row * 256 + kl);
      } else { afh[i] = zf; afl[i] = zf; }
    }
#pragma unroll
    for (int j = 0; j < 4; ++j) {
      int c = j * 16 + r16;         // col within 64-wide chunk
      bfh[j] = *(const bf16x8*)(BTh + (size_t)c * 768 + chunk * 256 + kl);
      bfl[j] = *(const bf16x8*)(BTl + (size_t)c * 768 + chunk * 256 + kl);
    }
#pragma unroll
    for (int i = 0; i < 2; ++i)
#pragma unroll
      for (int j = 0; j < 4; ++j) {
        acc[i][j] = __builtin_amdgcn_mfma_f32_16x16x32_bf16(afh[i], bfh[j], acc[i][j], 0, 0, 0);
        acc[i][j] = __builtin_amdgcn_mfma_f32_16x16x32_bf16(afh[i], bfl[j], acc[i][j], 0, 0, 0);
        acc[i][j] = __builtin_amdgcn_mfma_f32_16x16x32_bf16(afl[i], bfh[j], acc[i][j], 0, 0, 0);
      }
  }
  int qbase = (lane >> 4) * 4;
  int ccol = lane & 15;
#pragma unroll
  for (int i = 0; i < 2; ++i)
#pragma unroll
    for (int j = 0; j < 4; ++j) {
      int col = chunk * 64 + j * 16 + ccol;
#pragma unroll
      for (int q = 0; q < 4; ++q) {
        int row = m0 + i * 16 + qbase + q;
        if (row < M) P[(size_t)row * 192 + col] = f2bf(acc[i][j][q]);
      }
    }
}

// ---------------- final: out = logsoftmax(p0 + z1 + z2 + bias) ----------------
__global__ __launch_bounds__(256)
void final_lsm_kernel(const ushort* __restrict__ P, const float* __restrict__ Z1,
                      const float* __restrict__ Z2, const float* __restrict__ bias,
                      float* __restrict__ out, int Nn) {
  int row = blockIdx.x * 4 + (threadIdx.x >> 6);
  if (row >= Nn) return;
  int lane = threadIdx.x & 63;
  float v = bf2f(P[(size_t)row * 192 + lane]) + Z1[(size_t)row * 64 + lane] +
            Z2[(size_t)row * 64 + lane] + bias[lane];
  float m = v;
  for (int off = 32; off; off >>= 1) m = fmaxf(m, __shfl_xor(m, off));
  float ex = expf(v - m);
  float s = ex;
  for (int off = 32; off; off >>= 1) s += __shfl_xor(s, off);
  out[(size_t)row * 64 + lane] = v - m - logf(s);
}

extern "C" void kernel_launch(void* const* d_in, const int* in_sizes, int n_in,
                              void* d_out, int out_size, void* d_ws, size_t ws_size,
                              hipStream_t stream) {
  const float* x   = (const float*)d_in[0];
  const int* ei1   = (const int*)d_in[1];
  const float* ew1 = (const float*)d_in[2];
  const int* ei2   = (const int*)d_in[3];
  const float* ew2 = (const float*)d_in[4];
  int Nn = in_sizes[0] / 256;
  int E  = in_sizes[1] / 2;

  const float* ibW[3][3]; const float* ibB[3][3];
  int p = 5;
  for (int b = 0; b < 3; ++b)
    for (int q = 0; q < 3; ++q) {
      ibW[b][q] = (const float*)d_in[p++];
      ibB[b][q] = (const float*)d_in[p++];
    }
  const float* lnW[3] = {(const float*)d_in[23], (const float*)d_in[25], (const float*)d_in[27]};
  const float* lnb[3] = {(const float*)d_in[24], (const float*)d_in[26], (const float*)d_in[28]};
  int dmid[3] = {256, 256, 64}, dn[3] = {256, 256, 64};

  char* ws = (char*)d_ws;
  size_t off = 0;
  auto alloc = [&](size_t bytes) {
    void* pp = ws + off;
    off = (off + bytes + 255) & ~(size_t)255;
    return pp;
  };
  size_t act = (size_t)Nn * 256 * 2;  // one bf16 activation plane (25.6 MB)
  ushort* XAh = (ushort*)alloc(act); ushort* XAl = (ushort*)alloc(act);
  ushort* XBh = (ushort*)alloc(act); ushort* XBl = (ushort*)alloc(act);
  ushort* z1h = (ushort*)alloc(act); ushort* z1l = (ushort*)alloc(act);
  ushort* z2h = (ushort*)alloc(act); ushort* z2l = (ushort*)alloc(act);
  ushort* BTh[3]; ushort* BTl[3]; float* biasf[3];
  for (int b = 0; b < 3; ++b) {
    BTh[b]   = (ushort*)alloc((size_t)768 * dn[b] * 2);
    BTl[b]   = (ushort*)alloc((size_t)768 * dn[b] * 2);
    biasf[b] = (float*)alloc((size_t)dn[b] * 4);
  }
  int* offs[2]; int* cur[2]; int2* csr[2];
  const int* eis[2] = {ei1, ei2};
  const float* ews[2] = {ew1, ew2};
  for (int g = 0; g < 2; ++g) {
    offs[g] = (int*)alloc((size_t)(Nn + 1) * 4);
    cur[g]  = (int*)alloc((size_t)Nn * 4);
    csr[g]  = (int2*)alloc((size_t)E * 8);
  }
  // block-3 scratch aliased onto z-planes that are dead after block-2's GEMM:
  ushort* P   = z1h;                       // [Nn,192] bf16 = 19.2 MB <= 25.6 MB
  float*  Z1f = (float*)z1l;               // [Nn,64] f32 = 12.8 MB
  float*  Z2f = (float*)z2h;               // [Nn,64] f32 = 12.8 MB

  // weight fusion (split bf16, transposed [dn][768])
  for (int b = 0; b < 3; ++b) {
    int total = 768 * dn[b];
    fuse_w_kernel<<<(total + 255) / 256, 256, 0, stream>>>(
        ibW[b][0], ibW[b][1], ibW[b][2], lnW[b], BTh[b], BTl[b], dmid[b], dn[b]);
    fuse_b_kernel<<<dn[b], 256, 0, stream>>>(
        ibB[b][0], ibB[b][1], ibB[b][2], lnW[b], lnb[b], biasf[b], dmid[b], dn[b]);
  }

  // CSR build (per graph, reused by all 3 blocks)
  for (int g = 0; g < 2; ++g) {
    hipMemsetAsync(cur[g], 0, (size_t)Nn * 4, stream);
    hist_kernel<<<(E + 255) / 256, 256, 0, stream>>>(eis[g], cur[g], E);
    scan_kernel<<<1, 1024, 0, stream>>>(cur[g], offs[g], cur[g], Nn);
    fill_kernel<<<(E + 255) / 256, 256, 0, stream>>>(eis[g], ews[g], cur[g], csr[g], E);
  }

  // x -> bf16 hi/lo
  size_t n4 = (size_t)Nn * 64;
  conv_split_kernel<<<(int)((n4 + 255) / 256), 256, 0, stream>>>(x, XAh, XAl, n4);

  int aggGrid = (Nn + 3) / 4;
  dim3 gg((Nn + 63) / 64, 2);          // blocks 1-2 GEMM: 64x128 per block over dn=256
  dim3 gp((Nn + 127) / 128, 3);        // block-3 projection GEMM

  // block 1: in XA(x) -> out XB
  agg_bf16_kernel<<<aggGrid, 256, 0, stream>>>(offs[0], csr[0], XAh, z1h, z1l, Nn);
  agg_bf16_kernel<<<aggGrid, 256, 0, stream>>>(offs[1], csr[1], XAh, z2h, z2l, Nn);
  gemm_mfma32_kernel<<<gg, 256, 0, stream>>>(
      XAh, XAl, z1h, z1l, z2h, z2l, BTh[0], BTl[0], biasf[0], XBh, XBl, Nn, 256);

  // block 2: in XB -> out XA
  agg_bf16_kernel<<<aggGrid, 256, 0, stream>>>(offs[0], csr[0], XBh, z1h, z1l, Nn);
  agg_bf16_kernel<<<aggGrid, 256, 0, stream>>>(offs[1], csr[1], XBh, z2h, z2l, Nn);
  gemm_mfma32_kernel<<<gg, 256, 0, stream>>>(
      XBh, XBl, z1h, z1l, z2h, z2l, BTh[1], BTl[1], biasf[1], XAh, XAl, Nn, 256);

  // block 3 (projection-first): p = XA @ [M0|M1|M2]; z_g = agg_g(p chunk); out = p0+z1+z2+bias
  gemm_proj_kernel<<<gp, 256, 0, stream>>>(XAh, XAl, BTh[2], BTl[2], P, Nn);
  agg64_kernel<<<aggGrid, 256, 0, stream>>>(offs[0], csr[0], P, 64, Z1f, Nn);
  agg64_kernel<<<aggGrid, 256, 0, stream>>>(offs[1], csr[1], P, 128, Z2f, Nn);
  final_lsm_kernel<<<aggGrid, 256, 0, stream>>>(P, Z1f, Z2f, biasf[2], (float*)d_out, Nn);
}

// Round 11
// 2261.654 us; speedup vs baseline: 1.0180x; 1.0180x over previous
//
#include <hip/hip_runtime.h>
#include <math.h>

typedef __attribute__((ext_vector_type(8))) short bf16x8;
typedef __attribute__((ext_vector_type(4))) float f32x4;

__device__ inline ushort f2bf(float f) {
  unsigned u = __builtin_bit_cast(unsigned, f);
  unsigned r = (u + 0x7FFFu + ((u >> 16) & 1u)) >> 16;
  return (ushort)r;
}
__device__ inline float bf2f(ushort h) {
  return __builtin_bit_cast(float, (unsigned)h << 16);
}
__device__ inline void split2(float f, ushort& hi, ushort& lo) {
  hi = f2bf(f);
  lo = f2bf(f - bf2f(hi));
}

// ---------------- weight fusion: BT[c][r] = sum_t W_sub[i,t]*lnW[sub*dmid+t,c], r=sub*256+i
__global__ void fuse_w_kernel(const float* __restrict__ w0,
                              const float* __restrict__ w1,
                              const float* __restrict__ w2,
                              const float* __restrict__ lnW,
                              ushort* __restrict__ BTh, ushort* __restrict__ BTl,
                              int dmid, int dn) {
  int idx = blockIdx.x * blockDim.x + threadIdx.x;
  int total = 768 * dn;
  if (idx >= total) return;
  int r = idx / dn, c = idx - r * dn;
  int sub = r >> 8, i = r & 255;
  const float* W = (sub == 0) ? w0 : (sub == 1) ? w1 : w2;
  float acc = 0.f;
  for (int t = 0; t < dmid; ++t)
    acc += W[i * dmid + t] * lnW[(sub * dmid + t) * dn + c];
  ushort hi, lo; split2(acc, hi, lo);
  BTh[(size_t)c * 768 + r] = hi;
  BTl[(size_t)c * 768 + r] = lo;
}

// grid = dn blocks; 256 threads reduce 3*dmid terms for column c = blockIdx.x
__global__ __launch_bounds__(256)
void fuse_b_kernel(const float* __restrict__ b0,
                   const float* __restrict__ b1,
                   const float* __restrict__ b2,
                   const float* __restrict__ lnW,
                   const float* __restrict__ lnb,
                   float* __restrict__ biasf, int dmid, int dn) {
  int c = blockIdx.x;
  int t = threadIdx.x;
  float acc = 0.f;
  for (int k = t; k < 3 * dmid; k += 256) {
    int sub = k / dmid, w = k - sub * dmid;
    const float* bb = (sub == 0) ? b0 : (sub == 1) ? b1 : b2;
    acc += bb[w] * lnW[(size_t)k * dn + c];
  }
  for (int off = 32; off; off >>= 1) acc += __shfl_xor(acc, off);
  __shared__ float wsum[4];
  if ((t & 63) == 0) wsum[t >> 6] = acc;
  __syncthreads();
  if (t == 0) biasf[c] = lnb[c] + wsum[0] + wsum[1] + wsum[2] + wsum[3];
}

// ---------------- CSR build ----------------
__global__ void hist_kernel(const int* __restrict__ ei, int* cnt, int E) {
  int e = blockIdx.x * 256 + threadIdx.x;
  if (e < E) atomicAdd(&cnt[ei[E + e]], 1);
}

// single workgroup exclusive scan, wave-shuffle based
__global__ void scan_kernel(const int* cnt, int* offs, int* cur, int n) {
  __shared__ int wsum[16];
  __shared__ int running;
  int t = threadIdx.x;
  if (t == 0) running = 0;
  __syncthreads();
  for (int base = 0; base < n; base += 1024) {
    int i = base + t;
    int c = (i < n) ? cnt[i] : 0;
    int v = c;
#pragma unroll
    for (int off = 1; off < 64; off <<= 1) {
      int u = __shfl_up(v, off);
      if ((t & 63) >= off) v += u;
    }
    if ((t & 63) == 63) wsum[t >> 6] = v;
    __syncthreads();
    if (t < 16) {
      int s = wsum[t];
#pragma unroll
      for (int off = 1; off < 16; off <<= 1) {
        int u = __shfl_up(s, off, 16);
        if (t >= off) s += u;
      }
      wsum[t] = s;
    }
    __syncthreads();
    int wid6 = t >> 6;
    int waveoff = (wid6 == 0) ? 0 : wsum[wid6 - 1];
    int incl = v + waveoff;
    int r = running;
    if (i < n) { int ex = r + incl - c; offs[i] = ex; cur[i] = ex; }
    __syncthreads();
    if (t == 1023) running = r + incl;
    __syncthreads();
  }
  if (t == 0) offs[n] = running;
}

__global__ void fill_kernel(const int* __restrict__ ei, const float* __restrict__ ew,
                            int* cur, int2* __restrict__ csr, int E) {
  int e = blockIdx.x * 256 + threadIdx.x;
  if (e >= E) return;
  int dst = ei[E + e];
  int pos = atomicAdd(&cur[dst], 1);
  csr[pos] = make_int2(ei[e], __float_as_int(ew[e]));
}

// ---------------- x -> (hi,lo) bf16 split ----------------
__global__ void conv_split_kernel(const float* __restrict__ X,
                                  ushort* __restrict__ Xh, ushort* __restrict__ Xl,
                                  size_t n4) {
  size_t i = (size_t)blockIdx.x * 256 + threadIdx.x;
  if (i >= n4) return;
  float4 v = *(const float4*)(X + i * 4);
  ushort4 h, l;
  split2(v.x, h.x, l.x); split2(v.y, h.y, l.y);
  split2(v.z, h.z, l.z); split2(v.w, h.w, l.w);
  *(ushort4*)(Xh + i * 4) = h;
  *(ushort4*)(Xl + i * 4) = l;
}

// ---------------- aggregation (256-wide): one wave per dst row, bf16 gather ----------------
__global__ __launch_bounds__(256)
void agg_bf16_kernel(const int* __restrict__ offs, const int2* __restrict__ csr,
                     const ushort* __restrict__ Xh,
                     ushort* __restrict__ Zh, ushort* __restrict__ Zl, int Nn) {
  int wid = blockIdx.x * 4 + (threadIdx.x >> 6);
  if (wid >= Nn) return;
  int lane = threadIdx.x & 63;
  int beg = offs[wid], end = offs[wid + 1];
  float a0 = 0.f, a1 = 0.f, a2 = 0.f, a3 = 0.f;
  for (int i = beg; i < end; ++i) {
    int2 p = csr[i];
    float w = __int_as_float(p.y);
    ushort4 v = *(const ushort4*)(Xh + (size_t)p.x * 256 + lane * 4);
    a0 = fmaf(w, bf2f(v.x), a0);
    a1 = fmaf(w, bf2f(v.y), a1);
    a2 = fmaf(w, bf2f(v.z), a2);
    a3 = fmaf(w, bf2f(v.w), a3);
  }
  ushort4 h, l;
  split2(a0, h.x, l.x); split2(a1, h.y, l.y);
  split2(a2, h.z, l.z); split2(a3, h.w, l.w);
  *(ushort4*)(Zh + (size_t)wid * 256 + lane * 4) = h;
  *(ushort4*)(Zl + (size_t)wid * 256 + lane * 4) = l;
}

// ---------------- aggregation (64-wide): gather 128B slices of P[N,192] ----------------
__global__ __launch_bounds__(256)
void agg64_kernel(const int* __restrict__ offs, const int2* __restrict__ csr,
                  const ushort* __restrict__ P, int goff,
                  float* __restrict__ Z, int Nn) {
  int wid = blockIdx.x * 4 + (threadIdx.x >> 6);
  if (wid >= Nn) return;
  int lane = threadIdx.x & 63;
  int beg = offs[wid], end = offs[wid + 1];
  float acc = 0.f;
  for (int i = beg; i < end; ++i) {
    int2 p = csr[i];
    float w = __int_as_float(p.y);
    acc = fmaf(w, bf2f(P[(size_t)p.x * 192 + goff + lane]), acc);
  }
  Z[(size_t)wid * 64 + lane] = acc;
}

#define LOADA4(dsth, dstl, K0)                                           \
  {                                                                      \
    const ushort* ah_ = Ah[(K0) >> 8];                                   \
    const ushort* al_ = Al[(K0) >> 8];                                   \
    int kl_ = ((K0) & 255) + kg * 8;                                     \
    _Pragma("unroll")                                                    \
    for (int i = 0; i < 4; ++i) {                                        \
      int row_ = m0 + i * 16 + r16;                                      \
      if (row_ < M) {                                                    \
        dsth[i] = *(const bf16x8*)(ah_ + (size_t)row_ * 256 + kl_);      \
        dstl[i] = *(const bf16x8*)(al_ + (size_t)row_ * 256 + kl_);      \
      } else { dsth[i] = zf; dstl[i] = zf; }                             \
    }                                                                    \
  }

#define LOADB4(dsth, dstl, K0)                                           \
  {                                                                      \
    _Pragma("unroll")                                                    \
    for (int j = 0; j < 4; ++j) {                                        \
      int n_ = n0 + j * 16 + r16;                                        \
      dsth[j] = *(const bf16x8*)(BTh + (size_t)n_ * 768 + (K0) + kg * 8);\
      dstl[j] = *(const bf16x8*)(BTl + (size_t)n_ * 768 + (K0) + kg * 8);\
    }                                                                    \
  }

#define MFMA_CLUSTER(AH, AL, BH, BL, NI)                                 \
  {                                                                      \
    _Pragma("unroll")                                                    \
    for (int i = 0; i < NI; ++i)                                         \
      _Pragma("unroll")                                                  \
      for (int j = 0; j < 4; ++j) {                                      \
        acc[i][j] = __builtin_amdgcn_mfma_f32_16x16x32_bf16(AH[i], BH[j], acc[i][j], 0, 0, 0); \
        acc[i][j] = __builtin_amdgcn_mfma_f32_16x16x32_bf16(AH[i], BL[j], acc[i][j], 0, 0, 0); \
        acc[i][j] = __builtin_amdgcn_mfma_f32_16x16x32_bf16(AL[i], BH[j], acc[i][j], 0, 0, 0); \
      }                                                                  \
  }

// ---------------- MFMA GEMM blocks 1-2 (dn=256): 64x64 wave tile, 2-deep reg pipeline ----
// block = 4 waves side-by-side on n (w*64); one block per 64-row band -> A read once.
__global__ __launch_bounds__(256)
void gemm_mfma64_kernel(const ushort* __restrict__ A0h, const ushort* __restrict__ A0l,
                        const ushort* __restrict__ A1h, const ushort* __restrict__ A1l,
                        const ushort* __restrict__ A2h, const ushort* __restrict__ A2l,
                        const ushort* __restrict__ BTh, const ushort* __restrict__ BTl,
                        const float* __restrict__ bias,
                        ushort* __restrict__ Chi, ushort* __restrict__ Clo, int M) {
  int tid = threadIdx.x;
  int w = tid >> 6, lane = tid & 63;
  int m0 = blockIdx.x * 64;
  int n0 = w * 64;
  int r16 = lane & 15, kg = lane >> 4;
  const ushort* Ah[3] = {A0h, A1h, A2h};
  const ushort* Al[3] = {A0l, A1l, A2l};
  f32x4 acc[4][4] = {};
  const bf16x8 zf = {0, 0, 0, 0, 0, 0, 0, 0};

  bf16x8 a0h[4], a0l[4], a1h[4], a1l[4];
  bf16x8 b0h[4], b0l[4], b1h[4], b1l[4];
  LOADA4(a0h, a0l, 0); LOADB4(b0h, b0l, 0);
#pragma unroll 2
  for (int k0 = 0; k0 < 768; k0 += 64) {
    LOADA4(a1h, a1l, k0 + 32); LOADB4(b1h, b1l, k0 + 32);
    MFMA_CLUSTER(a0h, a0l, b0h, b0l, 4);
    if (k0 + 64 < 768) { LOADA4(a0h, a0l, k0 + 64); LOADB4(b0h, b0l, k0 + 64); }
    MFMA_CLUSTER(a1h, a1l, b1h, b1l, 4);
  }
  int qbase = (lane >> 4) * 4;
  int ccol = lane & 15;
#pragma unroll
  for (int i = 0; i < 4; ++i) {
#pragma unroll
    for (int j = 0; j < 4; ++j) {
      int col = n0 + j * 16 + ccol;
      float bv = bias[col];
#pragma unroll
      for (int q = 0; q < 4; ++q) {
        int row = m0 + i * 16 + qbase + q;
        if (row < M) {
          float c = acc[i][j][q] + bv;
          ushort hi, lo; split2(c, hi, lo);
          Chi[(size_t)row * 256 + col] = hi;
          Clo[(size_t)row * 256 + col] = lo;
        }
      }
    }
  }
}

// ---------------- block-3 projection GEMM: P = XA @ [M0|M1|M2], K=256, bf16 out ----------
// block = 384 thr = 6 waves: wm = w/3 (2 m-bands of 32), chunk = w%3; A read once per block.
__global__ __launch_bounds__(384)
void gemm_proj_kernel(const ushort* __restrict__ XAh, const ushort* __restrict__ XAl,
                      const ushort* __restrict__ BTh, const ushort* __restrict__ BTl,
                      ushort* __restrict__ P, int M) {
  int tid = threadIdx.x;
  int w = tid / 64, lane = tid & 63;
  int wm = w / 3, chunk = w - wm * 3;
  int m0 = blockIdx.x * 64 + wm * 32;
  int kbase = chunk * 256;
  int r16 = lane & 15, kg = lane >> 4;
  f32x4 acc[2][4] = {};
  const bf16x8 zf = {0, 0, 0, 0, 0, 0, 0, 0};

  bf16x8 a0h[2], a0l[2], a1h[2], a1l[2];
  bf16x8 b0h[4], b0l[4], b1h[4], b1l[4];

#define PLOADA(dsth, dstl, K0)                                           \
  {                                                                      \
    int kl_ = (K0) + kg * 8;                                             \
    _Pragma("unroll")                                                    \
    for (int i = 0; i < 2; ++i) {                                        \
      int row_ = m0 + i * 16 + r16;                                      \
      if (row_ < M) {                                                    \
        dsth[i] = *(const bf16x8*)(XAh + (size_t)row_ * 256 + kl_);      \
        dstl[i] = *(const bf16x8*)(XAl + (size_t)row_ * 256 + kl_);      \
      } else { dsth[i] = zf; dstl[i] = zf; }                             \
    }                                                                    \
  }
#define PLOADB(dsth, dstl, K0)                                           \
  {                                                                      \
    _Pragma("unroll")                                                    \
    for (int j = 0; j < 4; ++j) {                                        \
      int c_ = j * 16 + r16;                                             \
      dsth[j] = *(const bf16x8*)(BTh + (size_t)c_ * 768 + kbase + (K0) + kg * 8); \
      dstl[j] = *(const bf16x8*)(BTl + (size_t)c_ * 768 + kbase + (K0) + kg * 8); \
    }                                                                    \
  }

  PLOADA(a0h, a0l, 0); PLOADB(b0h, b0l, 0);
#pragma unroll 2
  for (int k0 = 0; k0 < 256; k0 += 64) {
    PLOADA(a1h, a1l, k0 + 32); PLOADB(b1h, b1l, k0 + 32);
    MFMA_CLUSTER(a0h, a0l, b0h, b0l, 2);
    if (k0 + 64 < 256) { PLOADA(a0h, a0l, k0 + 64); PLOADB(b0h, b0l, k0 + 64); }
    MFMA_CLUSTER(a1h, a1l, b1h, b1l, 2);
  }
  int qbase = (lane >> 4) * 4;
  int ccol = lane & 15;
#pragma unroll
  for (int i = 0; i < 2; ++i)
#pragma unroll
    for (int j = 0; j < 4; ++j) {
      int col = chunk * 64 + j * 16 + ccol;
#pragma unroll
      for (int q = 0; q < 4; ++q) {
        int row = m0 + i * 16 + qbase + q;
        if (row < M) P[(size_t)row * 192 + col] = f2bf(acc[i][j][q]);
      }
    }
}

// ---------------- final: out = logsoftmax(p0 + z1 + z2 + bias) ----------------
__global__ __launch_bounds__(256)
void final_lsm_kernel(const ushort* __restrict__ P, const float* __restrict__ Z1,
                      const float* __restrict__ Z2, const float* __restrict__ bias,
                      float* __restrict__ out, int Nn) {
  int row = blockIdx.x * 4 + (threadIdx.x >> 6);
  if (row >= Nn) return;
  int lane = threadIdx.x & 63;
  float v = bf2f(P[(size_t)row * 192 + lane]) + Z1[(size_t)row * 64 + lane] +
            Z2[(size_t)row * 64 + lane] + bias[lane];
  float m = v;
  for (int off = 32; off; off >>= 1) m = fmaxf(m, __shfl_xor(m, off));
  float ex = expf(v - m);
  float s = ex;
  for (int off = 32; off; off >>= 1) s += __shfl_xor(s, off);
  out[(size_t)row * 64 + lane] = v - m - logf(s);
}

extern "C" void kernel_launch(void* const* d_in, const int* in_sizes, int n_in,
                              void* d_out, int out_size, void* d_ws, size_t ws_size,
                              hipStream_t stream) {
  const float* x   = (const float*)d_in[0];
  const int* ei1   = (const int*)d_in[1];
  const float* ew1 = (const float*)d_in[2];
  const int* ei2   = (const int*)d_in[3];
  const float* ew2 = (const float*)d_in[4];
  int Nn = in_sizes[0] / 256;
  int E  = in_sizes[1] / 2;

  const float* ibW[3][3]; const float* ibB[3][3];
  int p = 5;
  for (int b = 0; b < 3; ++b)
    for (int q = 0; q < 3; ++q) {
      ibW[b][q] = (const float*)d_in[p++];
      ibB[b][q] = (const float*)d_in[p++];
    }
  const float* lnW[3] = {(const float*)d_in[23], (const float*)d_in[25], (const float*)d_in[27]};
  const float* lnb[3] = {(const float*)d_in[24], (const float*)d_in[26], (const float*)d_in[28]};
  int dmid[3] = {256, 256, 64}, dn[3] = {256, 256, 64};

  char* ws = (char*)d_ws;
  size_t off = 0;
  auto alloc = [&](size_t bytes) {
    void* pp = ws + off;
    off = (off + bytes + 255) & ~(size_t)255;
    return pp;
  };
  size_t act = (size_t)Nn * 256 * 2;  // one bf16 activation plane (25.6 MB)
  ushort* XAh = (ushort*)alloc(act); ushort* XAl = (ushort*)alloc(act);
  ushort* XBh = (ushort*)alloc(act); ushort* XBl = (ushort*)alloc(act);
  ushort* z1h = (ushort*)alloc(act); ushort* z1l = (ushort*)alloc(act);
  ushort* z2h = (ushort*)alloc(act); ushort* z2l = (ushort*)alloc(act);
  ushort* BTh[3]; ushort* BTl[3]; float* biasf[3];
  for (int b = 0; b < 3; ++b) {
    BTh[b]   = (ushort*)alloc((size_t)768 * dn[b] * 2);
    BTl[b]   = (ushort*)alloc((size_t)768 * dn[b] * 2);
    biasf[b] = (float*)alloc((size_t)dn[b] * 4);
  }
  int* offs[2]; int* cur[2]; int2* csr[2];
  const int* eis[2] = {ei1, ei2};
  const float* ews[2] = {ew1, ew2};
  for (int g = 0; g < 2; ++g) {
    offs[g] = (int*)alloc((size_t)(Nn + 1) * 4);
    cur[g]  = (int*)alloc((size_t)Nn * 4);
    csr[g]  = (int2*)alloc((size_t)E * 8);
  }
  // block-3 scratch aliased onto z-planes that are dead after block-2's GEMM:
  ushort* P   = z1h;                       // [Nn,192] bf16 = 19.2 MB <= 25.6 MB
  float*  Z1f = (float*)z1l;               // [Nn,64] f32 = 12.8 MB
  float*  Z2f = (float*)z2h;               // [Nn,64] f32 = 12.8 MB

  // weight fusion (split bf16, transposed [dn][768])
  for (int b = 0; b < 3; ++b) {
    int total = 768 * dn[b];
    fuse_w_kernel<<<(total + 255) / 256, 256, 0, stream>>>(
        ibW[b][0], ibW[b][1], ibW[b][2], lnW[b], BTh[b], BTl[b], dmid[b], dn[b]);
    fuse_b_kernel<<<dn[b], 256, 0, stream>>>(
        ibB[b][0], ibB[b][1], ibB[b][2], lnW[b], lnb[b], biasf[b], dmid[b], dn[b]);
  }

  // CSR build (per graph, reused by all 3 blocks)
  for (int g = 0; g < 2; ++g) {
    hipMemsetAsync(cur[g], 0, (size_t)Nn * 4, stream);
    hist_kernel<<<(E + 255) / 256, 256, 0, stream>>>(eis[g], cur[g], E);
    scan_kernel<<<1, 1024, 0, stream>>>(cur[g], offs[g], cur[g], Nn);
    fill_kernel<<<(E + 255) / 256, 256, 0, stream>>>(eis[g], ews[g], cur[g], csr[g], E);
  }

  // x -> bf16 hi/lo
  size_t n4 = (size_t)Nn * 64;
  conv_split_kernel<<<(int)((n4 + 255) / 256), 256, 0, stream>>>(x, XAh, XAl, n4);

  int aggGrid = (Nn + 3) / 4;
  int gg = (Nn + 63) / 64;             // blocks 1-2 GEMM: one block per 64-row band
  int gp = (Nn + 63) / 64;             // block-3 projection GEMM: 64-row band, 6 waves

  // block 1: in XA(x) -> out XB
  agg_bf16_kernel<<<aggGrid, 256, 0, stream>>>(offs[0], csr[0], XAh, z1h, z1l, Nn);
  agg_bf16_kernel<<<aggGrid, 256, 0, stream>>>(offs[1], csr[1], XAh, z2h, z2l, Nn);
  gemm_mfma64_kernel<<<gg, 256, 0, stream>>>(
      XAh, XAl, z1h, z1l, z2h, z2l, BTh[0], BTl[0], biasf[0], XBh, XBl, Nn);

  // block 2: in XB -> out XA
  agg_bf16_kernel<<<aggGrid, 256, 0, stream>>>(offs[0], csr[0], XBh, z1h, z1l, Nn);
  agg_bf16_kernel<<<aggGrid, 256, 0, stream>>>(offs[1], csr[1], XBh, z2h, z2l, Nn);
  gemm_mfma64_kernel<<<gg, 256, 0, stream>>>(
      XBh, XBl, z1h, z1l, z2h, z2l, BTh[1], BTl[1], biasf[1], XAh, XAl, Nn);

  // block 3 (projection-first): p = XA @ [M0|M1|M2]; z_g = agg_g(p chunk); out = p0+z1+z2+bias
  gemm_proj_kernel<<<gp, 384, 0, stream>>>(XAh, XAl, BTh[2], BTl[2], P, Nn);
  agg64_kernel<<<aggGrid, 256, 0, stream>>>(offs[0], csr[0], P, 64, Z1f, Nn);
  agg64_kernel<<<aggGrid, 256, 0, stream>>>(offs[1], csr[1], P, 128, Z2f, Nn);
  final_lsm_kernel<<<aggGrid, 256, 0, stream>>>(P, Z1f, Z2f, biasf[2], (float*)d_out, Nn);
}

// Round 12
// 2107.182 us; speedup vs baseline: 1.0926x; 1.0733x over previous
//
#include <hip/hip_runtime.h>
#include <math.h>

typedef __attribute__((ext_vector_type(8))) short bf16x8;
typedef __attribute__((ext_vector_type(4))) float f32x4;

__device__ inline ushort f2bf(float f) {
  unsigned u = __builtin_bit_cast(unsigned, f);
  unsigned r = (u + 0x7FFFu + ((u >> 16) & 1u)) >> 16;
  return (ushort)r;
}
__device__ inline float bf2f(ushort h) {
  return __builtin_bit_cast(float, (unsigned)h << 16);
}
__device__ inline void split2(float f, ushort& hi, ushort& lo) {
  hi = f2bf(f);
  lo = f2bf(f - bf2f(hi));
}

// ---------------- weight fusion: BT[c][r] (hi+lo bf16), r = sub*256 + i ----------------
__global__ void fuse_w_kernel(const float* __restrict__ w0,
                              const float* __restrict__ w1,
                              const float* __restrict__ w2,
                              const float* __restrict__ lnW,
                              ushort* __restrict__ BTh, ushort* __restrict__ BTl,
                              int dmid, int dn) {
  int idx = blockIdx.x * blockDim.x + threadIdx.x;
  int total = 768 * dn;
  if (idx >= total) return;
  int r = idx / dn, c = idx - r * dn;
  int sub = r >> 8, i = r & 255;
  const float* W = (sub == 0) ? w0 : (sub == 1) ? w1 : w2;
  float acc = 0.f;
  for (int t = 0; t < dmid; ++t)
    acc += W[i * dmid + t] * lnW[(sub * dmid + t) * dn + c];
  ushort hi, lo; split2(acc, hi, lo);
  BTh[(size_t)c * 768 + r] = hi;
  BTl[(size_t)c * 768 + r] = lo;
}

// grid = dn blocks; 256 threads reduce 3*dmid terms for column c = blockIdx.x
__global__ __launch_bounds__(256)
void fuse_b_kernel(const float* __restrict__ b0,
                   const float* __restrict__ b1,
                   const float* __restrict__ b2,
                   const float* __restrict__ lnW,
                   const float* __restrict__ lnb,
                   float* __restrict__ biasf, int dmid, int dn) {
  int c = blockIdx.x;
  int t = threadIdx.x;
  float acc = 0.f;
  for (int k = t; k < 3 * dmid; k += 256) {
    int sub = k / dmid, w = k - sub * dmid;
    const float* bb = (sub == 0) ? b0 : (sub == 1) ? b1 : b2;
    acc += bb[w] * lnW[(size_t)k * dn + c];
  }
  for (int off = 32; off; off >>= 1) acc += __shfl_xor(acc, off);
  __shared__ float wsum[4];
  if ((t & 63) == 0) wsum[t >> 6] = acc;
  __syncthreads();
  if (t == 0) biasf[c] = lnb[c] + wsum[0] + wsum[1] + wsum[2] + wsum[3];
}

// ---------------- CSR build ----------------
__global__ void hist_kernel(const int* __restrict__ ei, int* cnt, int E) {
  int e = blockIdx.x * 256 + threadIdx.x;
  if (e < E) atomicAdd(&cnt[ei[E + e]], 1);
}

// single workgroup exclusive scan, wave-shuffle based
__global__ void scan_kernel(const int* cnt, int* offs, int* cur, int n) {
  __shared__ int wsum[16];
  __shared__ int running;
  int t = threadIdx.x;
  if (t == 0) running = 0;
  __syncthreads();
  for (int base = 0; base < n; base += 1024) {
    int i = base + t;
    int c = (i < n) ? cnt[i] : 0;
    int v = c;
#pragma unroll
    for (int off = 1; off < 64; off <<= 1) {
      int u = __shfl_up(v, off);
      if ((t & 63) >= off) v += u;
    }
    if ((t & 63) == 63) wsum[t >> 6] = v;
    __syncthreads();
    if (t < 16) {
      int s = wsum[t];
#pragma unroll
      for (int off = 1; off < 16; off <<= 1) {
        int u = __shfl_up(s, off, 16);
        if (t >= off) s += u;
      }
      wsum[t] = s;
    }
    __syncthreads();
    int wid6 = t >> 6;
    int waveoff = (wid6 == 0) ? 0 : wsum[wid6 - 1];
    int incl = v + waveoff;
    int r = running;
    if (i < n) { int ex = r + incl - c; offs[i] = ex; cur[i] = ex; }
    __syncthreads();
    if (t == 1023) running = r + incl;
    __syncthreads();
  }
  if (t == 0) offs[n] = running;
}

__global__ void fill_kernel(const int* __restrict__ ei, const float* __restrict__ ew,
                            int* cur, int2* __restrict__ csr, int E) {
  int e = blockIdx.x * 256 + threadIdx.x;
  if (e >= E) return;
  int dst = ei[E + e];
  int pos = atomicAdd(&cur[dst], 1);
  csr[pos] = make_int2(ei[e], __float_as_int(ew[e]));
}

// ---------------- x -> bf16 (single plane) ----------------
__global__ void conv_bf16_kernel(const float* __restrict__ X,
                                 ushort* __restrict__ Xh, size_t n4) {
  size_t i = (size_t)blockIdx.x * 256 + threadIdx.x;
  if (i >= n4) return;
  float4 v = *(const float4*)(X + i * 4);
  ushort4 h;
  h.x = f2bf(v.x); h.y = f2bf(v.y); h.z = f2bf(v.z); h.w = f2bf(v.w);
  *(ushort4*)(Xh + i * 4) = h;
}

// ---------------- aggregation (256-wide): one wave per dst row, bf16 in/out ----------------
__global__ __launch_bounds__(256)
void agg_bf16_kernel(const int* __restrict__ offs, const int2* __restrict__ csr,
                     const ushort* __restrict__ Xh,
                     ushort* __restrict__ Zh, int Nn) {
  int wid = blockIdx.x * 4 + (threadIdx.x >> 6);
  if (wid >= Nn) return;
  int lane = threadIdx.x & 63;
  int beg = offs[wid], end = offs[wid + 1];
  float a0 = 0.f, a1 = 0.f, a2 = 0.f, a3 = 0.f;
  for (int i = beg; i < end; ++i) {
    int2 p = csr[i];
    float w = __int_as_float(p.y);
    ushort4 v = *(const ushort4*)(Xh + (size_t)p.x * 256 + lane * 4);
    a0 = fmaf(w, bf2f(v.x), a0);
    a1 = fmaf(w, bf2f(v.y), a1);
    a2 = fmaf(w, bf2f(v.z), a2);
    a3 = fmaf(w, bf2f(v.w), a3);
  }
  ushort4 h;
  h.x = f2bf(a0); h.y = f2bf(a1); h.z = f2bf(a2); h.w = f2bf(a3);
  *(ushort4*)(Zh + (size_t)wid * 256 + lane * 4) = h;
}

// ---------------- aggregation (64-wide): gather 128B slices of P[N,192] ----------------
__global__ __launch_bounds__(256)
void agg64_kernel(const int* __restrict__ offs, const int2* __restrict__ csr,
                  const ushort* __restrict__ P, int goff,
                  float* __restrict__ Z, int Nn) {
  int wid = blockIdx.x * 4 + (threadIdx.x >> 6);
  if (wid >= Nn) return;
  int lane = threadIdx.x & 63;
  int beg = offs[wid], end = offs[wid + 1];
  float acc = 0.f;
  for (int i = beg; i < end; ++i) {
    int2 p = csr[i];
    float w = __int_as_float(p.y);
    acc = fmaf(w, bf2f(P[(size_t)p.x * 192 + goff + lane]), acc);
  }
  Z[(size_t)wid * 64 + lane] = acc;
}

// A: single bf16 plane; B: hi+lo. 2 MFMAs per (i,j): Ah*Bh + Ah*Bl.
#define LOADA4(dst, K0)                                                  \
  {                                                                      \
    const ushort* a_ = Ap[(K0) >> 8];                                    \
    int kl_ = ((K0) & 255) + kg * 8;                                     \
    _Pragma("unroll")                                                    \
    for (int i = 0; i < 4; ++i) {                                        \
      int row_ = m0 + i * 16 + r16;                                      \
      dst[i] = (row_ < M) ? *(const bf16x8*)(a_ + (size_t)row_ * 256 + kl_) : zf; \
    }                                                                    \
  }

#define LOADB4(dsth, dstl, K0)                                           \
  {                                                                      \
    _Pragma("unroll")                                                    \
    for (int j = 0; j < 4; ++j) {                                        \
      int n_ = n0 + j * 16 + r16;                                        \
      dsth[j] = *(const bf16x8*)(BTh + (size_t)n_ * 768 + (K0) + kg * 8);\
      dstl[j] = *(const bf16x8*)(BTl + (size_t)n_ * 768 + (K0) + kg * 8);\
    }                                                                    \
  }

#define MFMA_CLUSTER(AH, BH, BL, NI)                                     \
  {                                                                      \
    _Pragma("unroll")                                                    \
    for (int i = 0; i < NI; ++i)                                         \
      _Pragma("unroll")                                                  \
      for (int j = 0; j < 4; ++j) {                                      \
        acc[i][j] = __builtin_amdgcn_mfma_f32_16x16x32_bf16(AH[i], BH[j], acc[i][j], 0, 0, 0); \
        acc[i][j] = __builtin_amdgcn_mfma_f32_16x16x32_bf16(AH[i], BL[j], acc[i][j], 0, 0, 0); \
      }                                                                  \
  }

// ---------------- MFMA GEMM blocks 1-2 (dn=256): 64x64 wave tile, 2-deep pipeline ----
// block = 4 waves side-by-side on n; one block per 64-row band -> A read once.
__global__ __launch_bounds__(256)
void gemm_mfma64_kernel(const ushort* __restrict__ A0, const ushort* __restrict__ A1,
                        const ushort* __restrict__ A2,
                        const ushort* __restrict__ BTh, const ushort* __restrict__ BTl,
                        const float* __restrict__ bias,
                        ushort* __restrict__ C, int M) {
  int tid = threadIdx.x;
  int w = tid >> 6, lane = tid & 63;
  int m0 = blockIdx.x * 64;
  int n0 = w * 64;
  int r16 = lane & 15, kg = lane >> 4;
  const ushort* Ap[3] = {A0, A1, A2};
  f32x4 acc[4][4] = {};
  const bf16x8 zf = {0, 0, 0, 0, 0, 0, 0, 0};

  bf16x8 a0[4], a1[4];
  bf16x8 b0h[4], b0l[4], b1h[4], b1l[4];
  LOADA4(a0, 0); LOADB4(b0h, b0l, 0);
#pragma unroll 2
  for (int k0 = 0; k0 < 768; k0 += 64) {
    LOADA4(a1, k0 + 32); LOADB4(b1h, b1l, k0 + 32);
    MFMA_CLUSTER(a0, b0h, b0l, 4);
    if (k0 + 64 < 768) { LOADA4(a0, k0 + 64); LOADB4(b0h, b0l, k0 + 64); }
    MFMA_CLUSTER(a1, b1h, b1l, 4);
  }
  int qbase = (lane >> 4) * 4;
  int ccol = lane & 15;
#pragma unroll
  for (int i = 0; i < 4; ++i) {
#pragma unroll
    for (int j = 0; j < 4; ++j) {
      int col = n0 + j * 16 + ccol;
      float bv = bias[col];
#pragma unroll
      for (int q = 0; q < 4; ++q) {
        int row = m0 + i * 16 + qbase + q;
        if (row < M) C[(size_t)row * 256 + col] = f2bf(acc[i][j][q] + bv);
      }
    }
  }
}

// ---------------- block-3 projection GEMM: P = XA @ [M0|M1|M2], K=256, bf16 out ----------
// block = 384 thr = 6 waves: wm = w/3 (2 m-bands of 32), chunk = w%3; A read once per block.
__global__ __launch_bounds__(384)
void gemm_proj_kernel(const ushort* __restrict__ XA,
                      const ushort* __restrict__ BTh, const ushort* __restrict__ BTl,
                      ushort* __restrict__ P, int M) {
  int tid = threadIdx.x;
  int w = tid / 64, lane = tid & 63;
  int wm = w / 3, chunk = w - wm * 3;
  int m0 = blockIdx.x * 64 + wm * 32;
  int kbase = chunk * 256;
  int r16 = lane & 15, kg = lane >> 4;
  f32x4 acc[2][4] = {};
  const bf16x8 zf = {0, 0, 0, 0, 0, 0, 0, 0};

  bf16x8 a0[2], a1[2];
  bf16x8 b0h[4], b0l[4], b1h[4], b1l[4];

#define PLOADA(dst, K0)                                                  \
  {                                                                      \
    int kl_ = (K0) + kg * 8;                                             \
    _Pragma("unroll")                                                    \
    for (int i = 0; i < 2; ++i) {                                        \
      int row_ = m0 + i * 16 + r16;                                      \
      dst[i] = (row_ < M) ? *(const bf16x8*)(XA + (size_t)row_ * 256 + kl_) : zf; \
    }                                                                    \
  }
#define PLOADB(dsth, dstl, K0)                                           \
  {                                                                      \
    _Pragma("unroll")                                                    \
    for (int j = 0; j < 4; ++j) {                                        \
      int c_ = j * 16 + r16;                                             \
      dsth[j] = *(const bf16x8*)(BTh + (size_t)c_ * 768 + kbase + (K0) + kg * 8); \
      dstl[j] = *(const bf16x8*)(BTl + (size_t)c_ * 768 + kbase + (K0) + kg * 8); \
    }                                                                    \
  }

  PLOADA(a0, 0); PLOADB(b0h, b0l, 0);
#pragma unroll 2
  for (int k0 = 0; k0 < 256; k0 += 64) {
    PLOADA(a1, k0 + 32); PLOADB(b1h, b1l, k0 + 32);
    MFMA_CLUSTER(a0, b0h, b0l, 2);
    if (k0 + 64 < 256) { PLOADA(a0, k0 + 64); PLOADB(b0h, b0l, k0 + 64); }
    MFMA_CLUSTER(a1, b1h, b1l, 2);
  }
  int qbase = (lane >> 4) * 4;
  int ccol = lane & 15;
#pragma unroll
  for (int i = 0; i < 2; ++i)
#pragma unroll
    for (int j = 0; j < 4; ++j) {
      int col = chunk * 64 + j * 16 + ccol;
#pragma unroll
      for (int q = 0; q < 4; ++q) {
        int row = m0 + i * 16 + qbase + q;
        if (row < M) P[(size_t)row * 192 + col] = f2bf(acc[i][j][q]);
      }
    }
}

// ---------------- final: out = logsoftmax(p0 + z1 + z2 + bias) ----------------
__global__ __launch_bounds__(256)
void final_lsm_kernel(const ushort* __restrict__ P, const float* __restrict__ Z1,
                      const float* __restrict__ Z2, const float* __restrict__ bias,
                      float* __restrict__ out, int Nn) {
  int row = blockIdx.x * 4 + (threadIdx.x >> 6);
  if (row >= Nn) return;
  int lane = threadIdx.x & 63;
  float v = bf2f(P[(size_t)row * 192 + lane]) + Z1[(size_t)row * 64 + lane] +
            Z2[(size_t)row * 64 + lane] + bias[lane];
  float m = v;
  for (int off = 32; off; off >>= 1) m = fmaxf(m, __shfl_xor(m, off));
  float ex = expf(v - m);
  float s = ex;
  for (int off = 32; off; off >>= 1) s += __shfl_xor(s, off);
  out[(size_t)row * 64 + lane] = v - m - logf(s);
}

extern "C" void kernel_launch(void* const* d_in, const int* in_sizes, int n_in,
                              void* d_out, int out_size, void* d_ws, size_t ws_size,
                              hipStream_t stream) {
  const float* x   = (const float*)d_in[0];
  const int* ei1   = (const int*)d_in[1];
  const float* ew1 = (const float*)d_in[2];
  const int* ei2   = (const int*)d_in[3];
  const float* ew2 = (const float*)d_in[4];
  int Nn = in_sizes[0] / 256;
  int E  = in_sizes[1] / 2;

  const float* ibW[3][3]; const float* ibB[3][3];
  int p = 5;
  for (int b = 0; b < 3; ++b)
    for (int q = 0; q < 3; ++q) {
      ibW[b][q] = (const float*)d_in[p++];
      ibB[b][q] = (const float*)d_in[p++];
    }
  const float* lnW[3] = {(const float*)d_in[23], (const float*)d_in[25], (const float*)d_in[27]};
  const float* lnb[3] = {(const float*)d_in[24], (const float*)d_in[26], (const float*)d_in[28]};
  int dmid[3] = {256, 256, 64}, dn[3] = {256, 256, 64};

  char* ws = (char*)d_ws;
  size_t off = 0;
  auto alloc = [&](size_t bytes) {
    void* pp = ws + off;
    off = (off + bytes + 255) & ~(size_t)255;
    return pp;
  };
  size_t act = (size_t)Nn * 256 * 2;  // one bf16 activation plane (25.6 MB)
  ushort* XA = (ushort*)alloc(act);
  ushort* XB = (ushort*)alloc(act);
  ushort* z1 = (ushort*)alloc(act);
  ushort* z2 = (ushort*)alloc(act);
  ushort* BTh[3]; ushort* BTl[3]; float* biasf[3];
  for (int b = 0; b < 3; ++b) {
    BTh[b]   = (ushort*)alloc((size_t)768 * dn[b] * 2);
    BTl[b]   = (ushort*)alloc((size_t)768 * dn[b] * 2);
    biasf[b] = (float*)alloc((size_t)dn[b] * 4);
  }
  int* offs[2]; int* cur[2]; int2* csr[2];
  const int* eis[2] = {ei1, ei2};
  const float* ews[2] = {ew1, ew2};
  for (int g = 0; g < 2; ++g) {
    offs[g] = (int*)alloc((size_t)(Nn + 1) * 4);
    cur[g]  = (int*)alloc((size_t)Nn * 4);
    csr[g]  = (int2*)alloc((size_t)E * 8);
  }
  // block-3 scratch aliased onto planes dead after block 2's GEMM:
  ushort* P   = XB;                        // [Nn,192] bf16 = 19.2 MB <= 25.6 MB (XB dead)
  float*  Z1f = (float*)z1;                // [Nn,64] f32 = 12.8 MB (z1 dead)
  float*  Z2f = (float*)z2;                // [Nn,64] f32 = 12.8 MB (z2 dead)

  // weight fusion (split bf16, transposed [dn][768])
  for (int b = 0; b < 3; ++b) {
    int total = 768 * dn[b];
    fuse_w_kernel<<<(total + 255) / 256, 256, 0, stream>>>(
        ibW[b][0], ibW[b][1], ibW[b][2], lnW[b], BTh[b], BTl[b], dmid[b], dn[b]);
    fuse_b_kernel<<<dn[b], 256, 0, stream>>>(
        ibB[b][0], ibB[b][1], ibB[b][2], lnW[b], lnb[b], biasf[b], dmid[b], dn[b]);
  }

  // CSR build (per graph, reused by all 3 blocks)
  for (int g = 0; g < 2; ++g) {
    hipMemsetAsync(cur[g], 0, (size_t)Nn * 4, stream);
    hist_kernel<<<(E + 255) / 256, 256, 0, stream>>>(eis[g], cur[g], E);
    scan_kernel<<<1, 1024, 0, stream>>>(cur[g], offs[g], cur[g], Nn);
    fill_kernel<<<(E + 255) / 256, 256, 0, stream>>>(eis[g], ews[g], cur[g], csr[g], E);
  }

  // x -> bf16
  size_t n4 = (size_t)Nn * 64;
  conv_bf16_kernel<<<(int)((n4 + 255) / 256), 256, 0, stream>>>(x, XA, n4);

  int aggGrid = (Nn + 3) / 4;
  int gg = (Nn + 63) / 64;

  // block 1: in XA(x) -> out XB
  agg_bf16_kernel<<<aggGrid, 256, 0, stream>>>(offs[0], csr[0], XA, z1, Nn);
  agg_bf16_kernel<<<aggGrid, 256, 0, stream>>>(offs[1], csr[1], XA, z2, Nn);
  gemm_mfma64_kernel<<<gg, 256, 0, stream>>>(
      XA, z1, z2, BTh[0], BTl[0], biasf[0], XB, Nn);

  // block 2: in XB -> out XA
  agg_bf16_kernel<<<aggGrid, 256, 0, stream>>>(offs[0], csr[0], XB, z1, Nn);
  agg_bf16_kernel<<<aggGrid, 256, 0, stream>>>(offs[1], csr[1], XB, z2, Nn);
  gemm_mfma64_kernel<<<gg, 256, 0, stream>>>(
      XB, z1, z2, BTh[1], BTl[1], biasf[1], XA, Nn);

  // block 3 (projection-first): p = XA @ [M0|M1|M2]; z_g = agg_g(p chunk); out = p0+z1+z2+bias
  gemm_proj_kernel<<<gg, 384, 0, stream>>>(XA, BTh[2], BTl[2], P, Nn);
  agg64_kernel<<<aggGrid, 256, 0, stream>>>(offs[0], csr[0], P, 64, Z1f, Nn);
  agg64_kernel<<<aggGrid, 256, 0, stream>>>(offs[1], csr[1], P, 128, Z2f, Nn);
  final_lsm_kernel<<<aggGrid, 256, 0, stream>>>(P, Z1f, Z2f, biasf[2], (float*)d_out, Nn);
}

// Round 13
// 1705.483 us; speedup vs baseline: 1.3499x; 1.2355x over previous
//
#include <hip/hip_runtime.h>
#include <math.h>

typedef __attribute__((ext_vector_type(8))) short bf16x8;
typedef __attribute__((ext_vector_type(4))) float f32x4;

__device__ inline ushort f2bf(float f) {
  unsigned u = __builtin_bit_cast(unsigned, f);
  unsigned r = (u + 0x7FFFu + ((u >> 16) & 1u)) >> 16;
  return (ushort)r;
}
__device__ inline float bf2f(ushort h) {
  return __builtin_bit_cast(float, (unsigned)h << 16);
}
__device__ inline void split2(float f, ushort& hi, ushort& lo) {
  hi = f2bf(f);
  lo = f2bf(f - bf2f(hi));
}

// ---------------- weight fusion: BT[c][r] (hi+lo bf16), r = sub*256 + i ----------------
__global__ void fuse_w_kernel(const float* __restrict__ w0,
                              const float* __restrict__ w1,
                              const float* __restrict__ w2,
                              const float* __restrict__ lnW,
                              ushort* __restrict__ BTh, ushort* __restrict__ BTl,
                              int dmid, int dn) {
  int idx = blockIdx.x * blockDim.x + threadIdx.x;
  int total = 768 * dn;
  if (idx >= total) return;
  int r = idx / dn, c = idx - r * dn;
  int sub = r >> 8, i = r & 255;
  const float* W = (sub == 0) ? w0 : (sub == 1) ? w1 : w2;
  float acc = 0.f;
  for (int t = 0; t < dmid; ++t)
    acc += W[i * dmid + t] * lnW[(sub * dmid + t) * dn + c];
  ushort hi, lo; split2(acc, hi, lo);
  BTh[(size_t)c * 768 + r] = hi;
  BTl[(size_t)c * 768 + r] = lo;
}

// grid = dn blocks; 256 threads reduce 3*dmid terms for column c = blockIdx.x
__global__ __launch_bounds__(256)
void fuse_b_kernel(const float* __restrict__ b0,
                   const float* __restrict__ b1,
                   const float* __restrict__ b2,
                   const float* __restrict__ lnW,
                   const float* __restrict__ lnb,
                   float* __restrict__ biasf, int dmid, int dn) {
  int c = blockIdx.x;
  int t = threadIdx.x;
  float acc = 0.f;
  for (int k = t; k < 3 * dmid; k += 256) {
    int sub = k / dmid, w = k - sub * dmid;
    const float* bb = (sub == 0) ? b0 : (sub == 1) ? b1 : b2;
    acc += bb[w] * lnW[(size_t)k * dn + c];
  }
  for (int off = 32; off; off >>= 1) acc += __shfl_xor(acc, off);
  __shared__ float wsum[4];
  if ((t & 63) == 0) wsum[t >> 6] = acc;
  __syncthreads();
  if (t == 0) biasf[c] = lnb[c] + wsum[0] + wsum[1] + wsum[2] + wsum[3];
}

// ---------------- CSR build ----------------
__global__ void hist_kernel(const int* __restrict__ ei, int* cnt, int E) {
  int e = blockIdx.x * 256 + threadIdx.x;
  if (e < E) atomicAdd(&cnt[ei[E + e]], 1);
}

// single workgroup exclusive scan, wave-shuffle based
__global__ void scan_kernel(const int* cnt, int* offs, int* cur, int n) {
  __shared__ int wsum[16];
  __shared__ int running;
  int t = threadIdx.x;
  if (t == 0) running = 0;
  __syncthreads();
  for (int base = 0; base < n; base += 1024) {
    int i = base + t;
    int c = (i < n) ? cnt[i] : 0;
    int v = c;
#pragma unroll
    for (int off = 1; off < 64; off <<= 1) {
      int u = __shfl_up(v, off);
      if ((t & 63) >= off) v += u;
    }
    if ((t & 63) == 63) wsum[t >> 6] = v;
    __syncthreads();
    if (t < 16) {
      int s = wsum[t];
#pragma unroll
      for (int off = 1; off < 16; off <<= 1) {
        int u = __shfl_up(s, off, 16);
        if (t >= off) s += u;
      }
      wsum[t] = s;
    }
    __syncthreads();
    int wid6 = t >> 6;
    int waveoff = (wid6 == 0) ? 0 : wsum[wid6 - 1];
    int incl = v + waveoff;
    int r = running;
    if (i < n) { int ex = r + incl - c; offs[i] = ex; cur[i] = ex; }
    __syncthreads();
    if (t == 1023) running = r + incl;
    __syncthreads();
  }
  if (t == 0) offs[n] = running;
}

__global__ void fill_kernel(const int* __restrict__ ei, const float* __restrict__ ew,
                            int* cur, int2* __restrict__ csr, int E) {
  int e = blockIdx.x * 256 + threadIdx.x;
  if (e >= E) return;
  int dst = ei[E + e];
  int pos = atomicAdd(&cur[dst], 1);
  csr[pos] = make_int2(ei[e], __float_as_int(ew[e]));
}

// ---------------- x -> bf16 (single plane) ----------------
__global__ void conv_bf16_kernel(const float* __restrict__ X,
                                 ushort* __restrict__ Xh, size_t n4) {
  size_t i = (size_t)blockIdx.x * 256 + threadIdx.x;
  if (i >= n4) return;
  float4 v = *(const float4*)(X + i * 4);
  ushort4 h;
  h.x = f2bf(v.x); h.y = f2bf(v.y); h.z = f2bf(v.z); h.w = f2bf(v.w);
  *(ushort4*)(Xh + i * 4) = h;
}

// ---------------- aggregation (256-wide): one wave per dst row, 4x unrolled gather ------
__global__ __launch_bounds__(256)
void agg_bf16_kernel(const int* __restrict__ offs, const int2* __restrict__ csr,
                     const ushort* __restrict__ Xh,
                     ushort* __restrict__ Zh, int Nn) {
  int wid = blockIdx.x * 4 + (threadIdx.x >> 6);
  if (wid >= Nn) return;
  int lane = threadIdx.x & 63;
  int beg = offs[wid], end = offs[wid + 1];
  float a0 = 0.f, a1 = 0.f, a2 = 0.f, a3 = 0.f;
  int i = beg;
  for (; i + 4 <= end; i += 4) {
    int2 p0 = csr[i], p1 = csr[i + 1], p2 = csr[i + 2], p3 = csr[i + 3];
    ushort4 v0 = *(const ushort4*)(Xh + (size_t)p0.x * 256 + lane * 4);
    ushort4 v1 = *(const ushort4*)(Xh + (size_t)p1.x * 256 + lane * 4);
    ushort4 v2 = *(const ushort4*)(Xh + (size_t)p2.x * 256 + lane * 4);
    ushort4 v3 = *(const ushort4*)(Xh + (size_t)p3.x * 256 + lane * 4);
    float w0 = __int_as_float(p0.y), w1 = __int_as_float(p1.y);
    float w2 = __int_as_float(p2.y), w3 = __int_as_float(p3.y);
    a0 = fmaf(w0, bf2f(v0.x), a0); a1 = fmaf(w0, bf2f(v0.y), a1);
    a2 = fmaf(w0, bf2f(v0.z), a2); a3 = fmaf(w0, bf2f(v0.w), a3);
    a0 = fmaf(w1, bf2f(v1.x), a0); a1 = fmaf(w1, bf2f(v1.y), a1);
    a2 = fmaf(w1, bf2f(v1.z), a2); a3 = fmaf(w1, bf2f(v1.w), a3);
    a0 = fmaf(w2, bf2f(v2.x), a0); a1 = fmaf(w2, bf2f(v2.y), a1);
    a2 = fmaf(w2, bf2f(v2.z), a2); a3 = fmaf(w2, bf2f(v2.w), a3);
    a0 = fmaf(w3, bf2f(v3.x), a0); a1 = fmaf(w3, bf2f(v3.y), a1);
    a2 = fmaf(w3, bf2f(v3.z), a2); a3 = fmaf(w3, bf2f(v3.w), a3);
  }
  for (; i < end; ++i) {
    int2 p = csr[i];
    float w = __int_as_float(p.y);
    ushort4 v = *(const ushort4*)(Xh + (size_t)p.x * 256 + lane * 4);
    a0 = fmaf(w, bf2f(v.x), a0); a1 = fmaf(w, bf2f(v.y), a1);
    a2 = fmaf(w, bf2f(v.z), a2); a3 = fmaf(w, bf2f(v.w), a3);
  }
  ushort4 h;
  h.x = f2bf(a0); h.y = f2bf(a1); h.z = f2bf(a2); h.w = f2bf(a3);
  *(ushort4*)(Zh + (size_t)wid * 256 + lane * 4) = h;
}

// ---------------- aggregation (64-wide): gather 128B slices of P[N,192], 4x unrolled ----
__global__ __launch_bounds__(256)
void agg64_kernel(const int* __restrict__ offs, const int2* __restrict__ csr,
                  const ushort* __restrict__ P, int goff,
                  float* __restrict__ Z, int Nn) {
  int wid = blockIdx.x * 4 + (threadIdx.x >> 6);
  if (wid >= Nn) return;
  int lane = threadIdx.x & 63;
  int beg = offs[wid], end = offs[wid + 1];
  float acc = 0.f;
  int i = beg;
  for (; i + 4 <= end; i += 4) {
    int2 p0 = csr[i], p1 = csr[i + 1], p2 = csr[i + 2], p3 = csr[i + 3];
    ushort v0 = P[(size_t)p0.x * 192 + goff + lane];
    ushort v1 = P[(size_t)p1.x * 192 + goff + lane];
    ushort v2 = P[(size_t)p2.x * 192 + goff + lane];
    ushort v3 = P[(size_t)p3.x * 192 + goff + lane];
    acc = fmaf(__int_as_float(p0.y), bf2f(v0), acc);
    acc = fmaf(__int_as_float(p1.y), bf2f(v1), acc);
    acc = fmaf(__int_as_float(p2.y), bf2f(v2), acc);
    acc = fmaf(__int_as_float(p3.y), bf2f(v3), acc);
  }
  for (; i < end; ++i) {
    int2 p = csr[i];
    acc = fmaf(__int_as_float(p.y), bf2f(P[(size_t)p.x * 192 + goff + lane]), acc);
  }
  Z[(size_t)wid * 64 + lane] = acc;
}

// A: single bf16 plane; B: hi+lo. 2 MFMAs per (i,j): Ah*Bh + Ah*Bl.
#define LOADA4(dst, K0)                                                  \
  {                                                                      \
    const ushort* a_ = Ap[(K0) >> 8];                                    \
    int kl_ = ((K0) & 255) + kg * 8;                                     \
    _Pragma("unroll")                                                    \
    for (int i = 0; i < 4; ++i) {                                        \
      int row_ = m0 + i * 16 + r16;                                      \
      dst[i] = (row_ < M) ? *(const bf16x8*)(a_ + (size_t)row_ * 256 + kl_) : zf; \
    }                                                                    \
  }

#define LOADB4(dsth, dstl, K0)                                           \
  {                                                                      \
    _Pragma("unroll")                                                    \
    for (int j = 0; j < 4; ++j) {                                        \
      int n_ = n0 + j * 16 + r16;                                        \
      dsth[j] = *(const bf16x8*)(BTh + (size_t)n_ * 768 + (K0) + kg * 8);\
      dstl[j] = *(const bf16x8*)(BTl + (size_t)n_ * 768 + (K0) + kg * 8);\
    }                                                                    \
  }

#define MFMA_CLUSTER(AH, BH, BL, NI)                                     \
  {                                                                      \
    _Pragma("unroll")                                                    \
    for (int i = 0; i < NI; ++i)                                         \
      _Pragma("unroll")                                                  \
      for (int j = 0; j < 4; ++j) {                                      \
        acc[i][j] = __builtin_amdgcn_mfma_f32_16x16x32_bf16(AH[i], BH[j], acc[i][j], 0, 0, 0); \
        acc[i][j] = __builtin_amdgcn_mfma_f32_16x16x32_bf16(AH[i], BL[j], acc[i][j], 0, 0, 0); \
      }                                                                  \
  }

// ---------------- MFMA GEMM blocks 1-2 (dn=256): 64x64 wave tile, 2-deep pipeline ----
__global__ __launch_bounds__(256)
void gemm_mfma64_kernel(const ushort* __restrict__ A0, const ushort* __restrict__ A1,
                        const ushort* __restrict__ A2,
                        const ushort* __restrict__ BTh, const ushort* __restrict__ BTl,
                        const float* __restrict__ bias,
                        ushort* __restrict__ C, int M) {
  int tid = threadIdx.x;
  int w = tid >> 6, lane = tid & 63;
  int m0 = blockIdx.x * 64;
  int n0 = w * 64;
  int r16 = lane & 15, kg = lane >> 4;
  const ushort* Ap[3] = {A0, A1, A2};
  f32x4 acc[4][4] = {};
  const bf16x8 zf = {0, 0, 0, 0, 0, 0, 0, 0};

  bf16x8 a0[4], a1[4];
  bf16x8 b0h[4], b0l[4], b1h[4], b1l[4];
  LOADA4(a0, 0); LOADB4(b0h, b0l, 0);
#pragma unroll 2
  for (int k0 = 0; k0 < 768; k0 += 64) {
    LOADA4(a1, k0 + 32); LOADB4(b1h, b1l, k0 + 32);
    MFMA_CLUSTER(a0, b0h, b0l, 4);
    if (k0 + 64 < 768) { LOADA4(a0, k0 + 64); LOADB4(b0h, b0l, k0 + 64); }
    MFMA_CLUSTER(a1, b1h, b1l, 4);
  }
  int qbase = (lane >> 4) * 4;
  int ccol = lane & 15;
#pragma unroll
  for (int i = 0; i < 4; ++i) {
#pragma unroll
    for (int j = 0; j < 4; ++j) {
      int col = n0 + j * 16 + ccol;
      float bv = bias[col];
#pragma unroll
      for (int q = 0; q < 4; ++q) {
        int row = m0 + i * 16 + qbase + q;
        if (row < M) C[(size_t)row * 256 + col] = f2bf(acc[i][j][q] + bv);
      }
    }
  }
}

// ---------------- block-3 projection GEMM: P = XA @ [M0|M1|M2], K=256, bf16 out ----------
__global__ __launch_bounds__(384)
void gemm_proj_kernel(const ushort* __restrict__ XA,
                      const ushort* __restrict__ BTh, const ushort* __restrict__ BTl,
                      ushort* __restrict__ P, int M) {
  int tid = threadIdx.x;
  int w = tid / 64, lane = tid & 63;
  int wm = w / 3, chunk = w - wm * 3;
  int m0 = blockIdx.x * 64 + wm * 32;
  int kbase = chunk * 256;
  int r16 = lane & 15, kg = lane >> 4;
  f32x4 acc[2][4] = {};
  const bf16x8 zf = {0, 0, 0, 0, 0, 0, 0, 0};

  bf16x8 a0[2], a1[2];
  bf16x8 b0h[4], b0l[4], b1h[4], b1l[4];

#define PLOADA(dst, K0)                                                  \
  {                                                                      \
    int kl_ = (K0) + kg * 8;                                             \
    _Pragma("unroll")                                                    \
    for (int i = 0; i < 2; ++i) {                                        \
      int row_ = m0 + i * 16 + r16;                                      \
      dst[i] = (row_ < M) ? *(const bf16x8*)(XA + (size_t)row_ * 256 + kl_) : zf; \
    }                                                                    \
  }
#define PLOADB(dsth, dstl, K0)                                           \
  {                                                                      \
    _Pragma("unroll")                                                    \
    for (int j = 0; j < 4; ++j) {                                        \
      int c_ = j * 16 + r16;                                             \
      dsth[j] = *(const bf16x8*)(BTh + (size_t)c_ * 768 + kbase + (K0) + kg * 8); \
      dstl[j] = *(const bf16x8*)(BTl + (size_t)c_ * 768 + kbase + (K0) + kg * 8); \
    }                                                                    \
  }

  PLOADA(a0, 0); PLOADB(b0h, b0l, 0);
#pragma unroll 2
  for (int k0 = 0; k0 < 256; k0 += 64) {
    PLOADA(a1, k0 + 32); PLOADB(b1h, b1l, k0 + 32);
    MFMA_CLUSTER(a0, b0h, b0l, 2);
    if (k0 + 64 < 256) { PLOADA(a0, k0 + 64); PLOADB(b0h, b0l, k0 + 64); }
    MFMA_CLUSTER(a1, b1h, b1l, 2);
  }
  int qbase = (lane >> 4) * 4;
  int ccol = lane & 15;
#pragma unroll
  for (int i = 0; i < 2; ++i)
#pragma unroll
    for (int j = 0; j < 4; ++j) {
      int col = chunk * 64 + j * 16 + ccol;
#pragma unroll
      for (int q = 0; q < 4; ++q) {
        int row = m0 + i * 16 + qbase + q;
        if (row < M) P[(size_t)row * 192 + col] = f2bf(acc[i][j][q]);
      }
    }
}

// ---------------- final: out = logsoftmax(p0 + z1 + z2 + bias) ----------------
__global__ __launch_bounds__(256)
void final_lsm_kernel(const ushort* __restrict__ P, const float* __restrict__ Z1,
                      const float* __restrict__ Z2, const float* __restrict__ bias,
                      float* __restrict__ out, int Nn) {
  int row = blockIdx.x * 4 + (threadIdx.x >> 6);
  if (row >= Nn) return;
  int lane = threadIdx.x & 63;
  float v = bf2f(P[(size_t)row * 192 + lane]) + Z1[(size_t)row * 64 + lane] +
            Z2[(size_t)row * 64 + lane] + bias[lane];
  float m = v;
  for (int off = 32; off; off >>= 1) m = fmaxf(m, __shfl_xor(m, off));
  float ex = expf(v - m);
  float s = ex;
  for (int off = 32; off; off >>= 1) s += __shfl_xor(s, off);
  out[(size_t)row * 64 + lane] = v - m - logf(s);
}

extern "C" void kernel_launch(void* const* d_in, const int* in_sizes, int n_in,
                              void* d_out, int out_size, void* d_ws, size_t ws_size,
                              hipStream_t stream) {
  const float* x   = (const float*)d_in[0];
  const int* ei1   = (const int*)d_in[1];
  const float* ew1 = (const float*)d_in[2];
  const int* ei2   = (const int*)d_in[3];
  const float* ew2 = (const float*)d_in[4];
  int Nn = in_sizes[0] / 256;
  int E  = in_sizes[1] / 2;

  const float* ibW[3][3]; const float* ibB[3][3];
  int p = 5;
  for (int b = 0; b < 3; ++b)
    for (int q = 0; q < 3; ++q) {
      ibW[b][q] = (const float*)d_in[p++];
      ibB[b][q] = (const float*)d_in[p++];
    }
  const float* lnW[3] = {(const float*)d_in[23], (const float*)d_in[25], (const float*)d_in[27]};
  const float* lnb[3] = {(const float*)d_in[24], (const float*)d_in[26], (const float*)d_in[28]};
  int dmid[3] = {256, 256, 64}, dn[3] = {256, 256, 64};

  char* ws = (char*)d_ws;
  size_t off = 0;
  auto alloc = [&](size_t bytes) {
    void* pp = ws + off;
    off = (off + bytes + 255) & ~(size_t)255;
    return pp;
  };
  size_t act = (size_t)Nn * 256 * 2;  // one bf16 activation plane (25.6 MB)
  ushort* XA = (ushort*)alloc(act);
  ushort* XB = (ushort*)alloc(act);
  ushort* z1 = (ushort*)alloc(act);
  ushort* z2 = (ushort*)alloc(act);
  ushort* BTh[3]; ushort* BTl[3]; float* biasf[3];
  for (int b = 0; b < 3; ++b) {
    BTh[b]   = (ushort*)alloc((size_t)768 * dn[b] * 2);
    BTl[b]   = (ushort*)alloc((size_t)768 * dn[b] * 2);
    biasf[b] = (float*)alloc((size_t)dn[b] * 4);
  }
  int* offs[2]; int* cur[2]; int2* csr[2];
  const int* eis[2] = {ei1, ei2};
  const float* ews[2] = {ew1, ew2};
  for (int g = 0; g < 2; ++g) {
    offs[g] = (int*)alloc((size_t)(Nn + 1) * 4);
    cur[g]  = (int*)alloc((size_t)Nn * 4);
    csr[g]  = (int2*)alloc((size_t)E * 8);
  }
  // block-3 scratch aliased onto planes dead after block 2's GEMM:
  ushort* P   = XB;                        // [Nn,192] bf16 = 19.2 MB <= 25.6 MB (XB dead)
  float*  Z1f = (float*)z1;                // [Nn,64] f32 = 12.8 MB (z1 dead)
  float*  Z2f = (float*)z2;                // [Nn,64] f32 = 12.8 MB (z2 dead)

  // weight fusion (split bf16, transposed [dn][768])
  for (int b = 0; b < 3; ++b) {
    int total = 768 * dn[b];
    fuse_w_kernel<<<(total + 255) / 256, 256, 0, stream>>>(
        ibW[b][0], ibW[b][1], ibW[b][2], lnW[b], BTh[b], BTl[b], dmid[b], dn[b]);
    fuse_b_kernel<<<dn[b], 256, 0, stream>>>(
        ibB[b][0], ibB[b][1], ibB[b][2], lnW[b], lnb[b], biasf[b], dmid[b], dn[b]);
  }

  // CSR build (per graph, reused by all 3 blocks)
  for (int g = 0; g < 2; ++g) {
    hipMemsetAsync(cur[g], 0, (size_t)Nn * 4, stream);
    hist_kernel<<<(E + 255) / 256, 256, 0, stream>>>(eis[g], cur[g], E);
    scan_kernel<<<1, 1024, 0, stream>>>(cur[g], offs[g], cur[g], Nn);
    fill_kernel<<<(E + 255) / 256, 256, 0, stream>>>(eis[g], ews[g], cur[g], csr[g], E);
  }

  // x -> bf16
  size_t n4 = (size_t)Nn * 64;
  conv_bf16_kernel<<<(int)((n4 + 255) / 256), 256, 0, stream>>>(x, XA, n4);

  int aggGrid = (Nn + 3) / 4;
  int gg = (Nn + 63) / 64;

  // block 1: in XA(x) -> out XB
  agg_bf16_kernel<<<aggGrid, 256, 0, stream>>>(offs[0], csr[0], XA, z1, Nn);
  agg_bf16_kernel<<<aggGrid, 256, 0, stream>>>(offs[1], csr[1], XA, z2, Nn);
  gemm_mfma64_kernel<<<gg, 256, 0, stream>>>(
      XA, z1, z2, BTh[0], BTl[0], biasf[0], XB, Nn);

  // block 2: in XB -> out XA
  agg_bf16_kernel<<<aggGrid, 256, 0, stream>>>(offs[0], csr[0], XB, z1, Nn);
  agg_bf16_kernel<<<aggGrid, 256, 0, stream>>>(offs[1], csr[1], XB, z2, Nn);
  gemm_mfma64_kernel<<<gg, 256, 0, stream>>>(
      XB, z1, z2, BTh[1], BTl[1], biasf[1], XA, Nn);

  // block 3 (projection-first): p = XA @ [M0|M1|M2]; z_g = agg_g(p chunk); out = p0+z1+z2+bias
  gemm_proj_kernel<<<gg, 384, 0, stream>>>(XA, BTh[2], BTl[2], P, Nn);
  agg64_kernel<<<aggGrid, 256, 0, stream>>>(offs[0], csr[0], P, 64, Z1f, Nn);
  agg64_kernel<<<aggGrid, 256, 0, stream>>>(offs[1], csr[1], P, 128, Z2f, Nn);
  final_lsm_kernel<<<aggGrid, 256, 0, stream>>>(P, Z1f, Z2f, biasf[2], (float*)d_out, Nn);
}

// Round 14
// 1562.992 us; speedup vs baseline: 1.4730x; 1.0912x over previous
//
#include <hip/hip_runtime.h>
#include <math.h>

typedef __attribute__((ext_vector_type(8))) short bf16x8;
typedef __attribute__((ext_vector_type(4))) float f32x4;

__device__ inline ushort f2bf(float f) {
  unsigned u = __builtin_bit_cast(unsigned, f);
  unsigned r = (u + 0x7FFFu + ((u >> 16) & 1u)) >> 16;
  return (ushort)r;
}
__device__ inline float bf2f(ushort h) {
  return __builtin_bit_cast(float, (unsigned)h << 16);
}
__device__ inline void split2(float f, ushort& hi, ushort& lo) {
  hi = f2bf(f);
  lo = f2bf(f - bf2f(hi));
}

// ---------------- weight fusion: BT[c][r] (hi+lo), r = sub*256 + i ----------------
// one thread per (r, 4-col quad); float4 lnW loads, 4x t-unroll -> 16 indep FMA chains
__global__ __launch_bounds__(256)
void fuse_w_kernel(const float* __restrict__ w0,
                   const float* __restrict__ w1,
                   const float* __restrict__ w2,
                   const float* __restrict__ lnW,
                   ushort* __restrict__ BTh, ushort* __restrict__ BTl,
                   int dmid, int dn) {
  int tid = blockIdx.x * blockDim.x + threadIdx.x;
  int nq = dn >> 2;
  int total = 768 * nq;
  if (tid >= total) return;
  int r = tid / nq, cq = tid - r * nq;
  int c0 = cq * 4;
  int sub = r >> 8, i = r & 255;
  const float* W = (sub == 0) ? w0 : (sub == 1) ? w1 : w2;
  const float* Wrow = W + (size_t)i * dmid;
  const float* Lbase = lnW + (size_t)sub * dmid * dn + c0;
  float acc0 = 0.f, acc1 = 0.f, acc2 = 0.f, acc3 = 0.f;
  for (int t = 0; t < dmid; t += 4) {
    float wa = Wrow[t], wb = Wrow[t + 1], wc = Wrow[t + 2], wd = Wrow[t + 3];
    float4 la = *(const float4*)(Lbase + (size_t)t * dn);
    float4 lb = *(const float4*)(Lbase + (size_t)(t + 1) * dn);
    float4 lc = *(const float4*)(Lbase + (size_t)(t + 2) * dn);
    float4 ld = *(const float4*)(Lbase + (size_t)(t + 3) * dn);
    acc0 = fmaf(wa, la.x, acc0); acc1 = fmaf(wa, la.y, acc1);
    acc2 = fmaf(wa, la.z, acc2); acc3 = fmaf(wa, la.w, acc3);
    acc0 = fmaf(wb, lb.x, acc0); acc1 = fmaf(wb, lb.y, acc1);
    acc2 = fmaf(wb, lb.z, acc2); acc3 = fmaf(wb, lb.w, acc3);
    acc0 = fmaf(wc, lc.x, acc0); acc1 = fmaf(wc, lc.y, acc1);
    acc2 = fmaf(wc, lc.z, acc2); acc3 = fmaf(wc, lc.w, acc3);
    acc0 = fmaf(wd, ld.x, acc0); acc1 = fmaf(wd, ld.y, acc1);
    acc2 = fmaf(wd, ld.z, acc2); acc3 = fmaf(wd, ld.w, acc3);
  }
  float a4[4] = {acc0, acc1, acc2, acc3};
#pragma unroll
  for (int j = 0; j < 4; ++j) {
    ushort hi, lo; split2(a4[j], hi, lo);
    BTh[(size_t)(c0 + j) * 768 + r] = hi;
    BTl[(size_t)(c0 + j) * 768 + r] = lo;
  }
}

// grid = dn blocks; 256 threads reduce 3*dmid terms for column c = blockIdx.x
__global__ __launch_bounds__(256)
void fuse_b_kernel(const float* __restrict__ b0,
                   const float* __restrict__ b1,
                   const float* __restrict__ b2,
                   const float* __restrict__ lnW,
                   const float* __restrict__ lnb,
                   float* __restrict__ biasf, int dmid, int dn) {
  int c = blockIdx.x;
  int t = threadIdx.x;
  float acc = 0.f;
  for (int k = t; k < 3 * dmid; k += 256) {
    int sub = k / dmid, w = k - sub * dmid;
    const float* bb = (sub == 0) ? b0 : (sub == 1) ? b1 : b2;
    acc += bb[w] * lnW[(size_t)k * dn + c];
  }
  for (int off = 32; off; off >>= 1) acc += __shfl_xor(acc, off);
  __shared__ float wsum[4];
  if ((t & 63) == 0) wsum[t >> 6] = acc;
  __syncthreads();
  if (t == 0) biasf[c] = lnb[c] + wsum[0] + wsum[1] + wsum[2] + wsum[3];
}

// ---------------- CSR build ----------------
__global__ void hist_kernel(const int* __restrict__ ei, int* cnt, int E) {
  int e = blockIdx.x * 256 + threadIdx.x;
  if (e < E) atomicAdd(&cnt[ei[E + e]], 1);
}

// single workgroup exclusive scan, wave-shuffle based
__global__ void scan_kernel(const int* cnt, int* offs, int* cur, int n) {
  __shared__ int wsum[16];
  __shared__ int running;
  int t = threadIdx.x;
  if (t == 0) running = 0;
  __syncthreads();
  for (int base = 0; base < n; base += 1024) {
    int i = base + t;
    int c = (i < n) ? cnt[i] : 0;
    int v = c;
#pragma unroll
    for (int off = 1; off < 64; off <<= 1) {
      int u = __shfl_up(v, off);
      if ((t & 63) >= off) v += u;
    }
    if ((t & 63) == 63) wsum[t >> 6] = v;
    __syncthreads();
    if (t < 16) {
      int s = wsum[t];
#pragma unroll
      for (int off = 1; off < 16; off <<= 1) {
        int u = __shfl_up(s, off, 16);
        if (t >= off) s += u;
      }
      wsum[t] = s;
    }
    __syncthreads();
    int wid6 = t >> 6;
    int waveoff = (wid6 == 0) ? 0 : wsum[wid6 - 1];
    int incl = v + waveoff;
    int r = running;
    if (i < n) { int ex = r + incl - c; offs[i] = ex; cur[i] = ex; }
    __syncthreads();
    if (t == 1023) running = r + incl;
    __syncthreads();
  }
  if (t == 0) offs[n] = running;
}

__global__ void fill_kernel(const int* __restrict__ ei, const float* __restrict__ ew,
                            int* cur, int2* __restrict__ csr, int E) {
  int e = blockIdx.x * 256 + threadIdx.x;
  if (e >= E) return;
  int dst = ei[E + e];
  int pos = atomicAdd(&cur[dst], 1);
  csr[pos] = make_int2(ei[e], __float_as_int(ew[e]));
}

// ---------------- x -> bf16 (single plane) ----------------
__global__ void conv_bf16_kernel(const float* __restrict__ X,
                                 ushort* __restrict__ Xh, size_t n4) {
  size_t i = (size_t)blockIdx.x * 256 + threadIdx.x;
  if (i >= n4) return;
  float4 v = *(const float4*)(X + i * 4);
  ushort4 h;
  h.x = f2bf(v.x); h.y = f2bf(v.y); h.z = f2bf(v.z); h.w = f2bf(v.w);
  *(ushort4*)(Xh + i * 4) = h;
}

// ---------------- aggregation (256-wide): one wave per dst row, 8x unrolled gather ------
__global__ __launch_bounds__(256)
void agg_bf16_kernel(const int* __restrict__ offs, const int2* __restrict__ csr,
                     const ushort* __restrict__ Xh,
                     ushort* __restrict__ Zh, int Nn) {
  int wid = blockIdx.x * 4 + (threadIdx.x >> 6);
  if (wid >= Nn) return;
  int lane = threadIdx.x & 63;
  int beg = offs[wid], end = offs[wid + 1];
  float a0 = 0.f, a1 = 0.f, a2 = 0.f, a3 = 0.f;
  int i = beg;
  for (; i + 8 <= end; i += 8) {
    int2 p[8];
    ushort4 v[8];
#pragma unroll
    for (int u = 0; u < 8; ++u) p[u] = csr[i + u];
#pragma unroll
    for (int u = 0; u < 8; ++u)
      v[u] = *(const ushort4*)(Xh + (size_t)p[u].x * 256 + lane * 4);
#pragma unroll
    for (int u = 0; u < 8; ++u) {
      float w = __int_as_float(p[u].y);
      a0 = fmaf(w, bf2f(v[u].x), a0); a1 = fmaf(w, bf2f(v[u].y), a1);
      a2 = fmaf(w, bf2f(v[u].z), a2); a3 = fmaf(w, bf2f(v[u].w), a3);
    }
  }
  for (; i < end; ++i) {
    int2 p = csr[i];
    float w = __int_as_float(p.y);
    ushort4 v = *(const ushort4*)(Xh + (size_t)p.x * 256 + lane * 4);
    a0 = fmaf(w, bf2f(v.x), a0); a1 = fmaf(w, bf2f(v.y), a1);
    a2 = fmaf(w, bf2f(v.z), a2); a3 = fmaf(w, bf2f(v.w), a3);
  }
  ushort4 h;
  h.x = f2bf(a0); h.y = f2bf(a1); h.z = f2bf(a2); h.w = f2bf(a3);
  *(ushort4*)(Zh + (size_t)wid * 256 + lane * 4) = h;
}

// ---------------- aggregation (64-wide): gather 128B slices of P[N,192], 8x unrolled ----
__global__ __launch_bounds__(256)
void agg64_kernel(const int* __restrict__ offs, const int2* __restrict__ csr,
                  const ushort* __restrict__ P, int goff,
                  float* __restrict__ Z, int Nn) {
  int wid = blockIdx.x * 4 + (threadIdx.x >> 6);
  if (wid >= Nn) return;
  int lane = threadIdx.x & 63;
  int beg = offs[wid], end = offs[wid + 1];
  float acc = 0.f;
  int i = beg;
  for (; i + 8 <= end; i += 8) {
    int2 p[8];
    ushort v[8];
#pragma unroll
    for (int u = 0; u < 8; ++u) p[u] = csr[i + u];
#pragma unroll
    for (int u = 0; u < 8; ++u) v[u] = P[(size_t)p[u].x * 192 + goff + lane];
#pragma unroll
    for (int u = 0; u < 8; ++u)
      acc = fmaf(__int_as_float(p[u].y), bf2f(v[u]), acc);
  }
  for (; i < end; ++i) {
    int2 p = csr[i];
    acc = fmaf(__int_as_float(p.y), bf2f(P[(size_t)p.x * 192 + goff + lane]), acc);
  }
  Z[(size_t)wid * 64 + lane] = acc;
}

// A: single bf16 plane; B: hi+lo. 2 MFMAs per (i,j): Ah*Bh + Ah*Bl.
#define LOADA4(dst, K0)                                                  \
  {                                                                      \
    const ushort* a_ = Ap[(K0) >> 8];                                    \
    int kl_ = ((K0) & 255) + kg * 8;                                     \
    _Pragma("unroll")                                                    \
    for (int i = 0; i < 4; ++i) {                                        \
      int row_ = m0 + i * 16 + r16;                                      \
      dst[i] = (row_ < M) ? *(const bf16x8*)(a_ + (size_t)row_ * 256 + kl_) : zf; \
    }                                                                    \
  }

#define LOADB4(dsth, dstl, K0)                                           \
  {                                                                      \
    _Pragma("unroll")                                                    \
    for (int j = 0; j < 4; ++j) {                                        \
      int n_ = n0 + j * 16 + r16;                                        \
      dsth[j] = *(const bf16x8*)(BTh + (size_t)n_ * 768 + (K0) + kg * 8);\
      dstl[j] = *(const bf16x8*)(BTl + (size_t)n_ * 768 + (K0) + kg * 8);\
    }                                                                    \
  }

#define MFMA_CLUSTER(AH, BH, BL, NI)                                     \
  {                                                                      \
    _Pragma("unroll")                                                    \
    for (int i = 0; i < NI; ++i)                                         \
      _Pragma("unroll")                                                  \
      for (int j = 0; j < 4; ++j) {                                      \
        acc[i][j] = __builtin_amdgcn_mfma_f32_16x16x32_bf16(AH[i], BH[j], acc[i][j], 0, 0, 0); \
        acc[i][j] = __builtin_amdgcn_mfma_f32_16x16x32_bf16(AH[i], BL[j], acc[i][j], 0, 0, 0); \
      }                                                                  \
  }

// ---------------- MFMA GEMM blocks 1-2 (dn=256): 64x64 wave tile, 2-deep pipeline ----
__global__ __launch_bounds__(256)
void gemm_mfma64_kernel(const ushort* __restrict__ A0, const ushort* __restrict__ A1,
                        const ushort* __restrict__ A2,
                        const ushort* __restrict__ BTh, const ushort* __restrict__ BTl,
                        const float* __restrict__ bias,
                        ushort* __restrict__ C, int M) {
  int tid = threadIdx.x;
  int w = tid >> 6, lane = tid & 63;
  int m0 = blockIdx.x * 64;
  int n0 = w * 64;
  int r16 = lane & 15, kg = lane >> 4;
  const ushort* Ap[3] = {A0, A1, A2};
  f32x4 acc[4][4] = {};
  const bf16x8 zf = {0, 0, 0, 0, 0, 0, 0, 0};

  bf16x8 a0[4], a1[4];
  bf16x8 b0h[4], b0l[4], b1h[4], b1l[4];
  LOADA4(a0, 0); LOADB4(b0h, b0l, 0);
#pragma unroll 2
  for (int k0 = 0; k0 < 768; k0 += 64) {
    LOADA4(a1, k0 + 32); LOADB4(b1h, b1l, k0 + 32);
    MFMA_CLUSTER(a0, b0h, b0l, 4);
    if (k0 + 64 < 768) { LOADA4(a0, k0 + 64); LOADB4(b0h, b0l, k0 + 64); }
    MFMA_CLUSTER(a1, b1h, b1l, 4);
  }
  int qbase = (lane >> 4) * 4;
  int ccol = lane & 15;
#pragma unroll
  for (int i = 0; i < 4; ++i) {
#pragma unroll
    for (int j = 0; j < 4; ++j) {
      int col = n0 + j * 16 + ccol;
      float bv = bias[col];
#pragma unroll
      for (int q = 0; q < 4; ++q) {
        int row = m0 + i * 16 + qbase + q;
        if (row < M) C[(size_t)row * 256 + col] = f2bf(acc[i][j][q] + bv);
      }
    }
  }
}

// ---------------- block-3 projection GEMM: P = XA @ [M0|M1|M2], K=256, bf16 out ----------
__global__ __launch_bounds__(384)
void gemm_proj_kernel(const ushort* __restrict__ XA,
                      const ushort* __restrict__ BTh, const ushort* __restrict__ BTl,
                      ushort* __restrict__ P, int M) {
  int tid = threadIdx.x;
  int w = tid / 64, lane = tid & 63;
  int wm = w / 3, chunk = w - wm * 3;
  int m0 = blockIdx.x * 64 + wm * 32;
  int kbase = chunk * 256;
  int r16 = lane & 15, kg = lane >> 4;
  f32x4 acc[2][4] = {};
  const bf16x8 zf = {0, 0, 0, 0, 0, 0, 0, 0};

  bf16x8 a0[2], a1[2];
  bf16x8 b0h[4], b0l[4], b1h[4], b1l[4];

#define PLOADA(dst, K0)                                                  \
  {                                                                      \
    int kl_ = (K0) + kg * 8;                                             \
    _Pragma("unroll")                                                    \
    for (int i = 0; i < 2; ++i) {                                        \
      int row_ = m0 + i * 16 + r16;                                      \
      dst[i] = (row_ < M) ? *(const bf16x8*)(XA + (size_t)row_ * 256 + kl_) : zf; \
    }                                                                    \
  }
#define PLOADB(dsth, dstl, K0)                                           \
  {                                                                      \
    _Pragma("unroll")                                                    \
    for (int j = 0; j < 4; ++j) {                                        \
      int c_ = j * 16 + r16;                                             \
      dsth[j] = *(const bf16x8*)(BTh + (size_t)c_ * 768 + kbase + (K0) + kg * 8); \
      dstl[j] = *(const bf16x8*)(BTl + (size_t)c_ * 768 + kbase + (K0) + kg * 8); \
    }                                                                    \
  }

  PLOADA(a0, 0); PLOADB(b0h, b0l, 0);
#pragma unroll 2
  for (int k0 = 0; k0 < 256; k0 += 64) {
    PLOADA(a1, k0 + 32); PLOADB(b1h, b1l, k0 + 32);
    MFMA_CLUSTER(a0, b0h, b0l, 2);
    if (k0 + 64 < 256) { PLOADA(a0, k0 + 64); PLOADB(b0h, b0l, k0 + 64); }
    MFMA_CLUSTER(a1, b1h, b1l, 2);
  }
  int qbase = (lane >> 4) * 4;
  int ccol = lane & 15;
#pragma unroll
  for (int i = 0; i < 2; ++i)
#pragma unroll
    for (int j = 0; j < 4; ++j) {
      int col = chunk * 64 + j * 16 + ccol;
#pragma unroll
      for (int q = 0; q < 4; ++q) {
        int row = m0 + i * 16 + qbase + q;
        if (row < M) P[(size_t)row * 192 + col] = f2bf(acc[i][j][q]);
      }
    }
}

// ---------------- final: out = logsoftmax(p0 + z1 + z2 + bias) ----------------
__global__ __launch_bounds__(256)
void final_lsm_kernel(const ushort* __restrict__ P, const float* __restrict__ Z1,
                      const float* __restrict__ Z2, const float* __restrict__ bias,
                      float* __restrict__ out, int Nn) {
  int row = blockIdx.x * 4 + (threadIdx.x >> 6);
  if (row >= Nn) return;
  int lane = threadIdx.x & 63;
  float v = bf2f(P[(size_t)row * 192 + lane]) + Z1[(size_t)row * 64 + lane] +
            Z2[(size_t)row * 64 + lane] + bias[lane];
  float m = v;
  for (int off = 32; off; off >>= 1) m = fmaxf(m, __shfl_xor(m, off));
  float ex = expf(v - m);
  float s = ex;
  for (int off = 32; off; off >>= 1) s += __shfl_xor(s, off);
  out[(size_t)row * 64 + lane] = v - m - logf(s);
}

extern "C" void kernel_launch(void* const* d_in, const int* in_sizes, int n_in,
                              void* d_out, int out_size, void* d_ws, size_t ws_size,
                              hipStream_t stream) {
  const float* x   = (const float*)d_in[0];
  const int* ei1   = (const int*)d_in[1];
  const float* ew1 = (const float*)d_in[2];
  const int* ei2   = (const int*)d_in[3];
  const float* ew2 = (const float*)d_in[4];
  int Nn = in_sizes[0] / 256;
  int E  = in_sizes[1] / 2;

  const float* ibW[3][3]; const float* ibB[3][3];
  int p = 5;
  for (int b = 0; b < 3; ++b)
    for (int q = 0; q < 3; ++q) {
      ibW[b][q] = (const float*)d_in[p++];
      ibB[b][q] = (const float*)d_in[p++];
    }
  const float* lnW[3] = {(const float*)d_in[23], (const float*)d_in[25], (const float*)d_in[27]};
  const float* lnb[3] = {(const float*)d_in[24], (const float*)d_in[26], (const float*)d_in[28]};
  int dmid[3] = {256, 256, 64}, dn[3] = {256, 256, 64};

  char* ws = (char*)d_ws;
  size_t off = 0;
  auto alloc = [&](size_t bytes) {
    void* pp = ws + off;
    off = (off + bytes + 255) & ~(size_t)255;
    return pp;
  };
  size_t act = (size_t)Nn * 256 * 2;  // one bf16 activation plane (25.6 MB)
  ushort* XA = (ushort*)alloc(act);
  ushort* XB = (ushort*)alloc(act);
  ushort* z1 = (ushort*)alloc(act);
  ushort* z2 = (ushort*)alloc(act);
  ushort* BTh[3]; ushort* BTl[3]; float* biasf[3];
  for (int b = 0; b < 3; ++b) {
    BTh[b]   = (ushort*)alloc((size_t)768 * dn[b] * 2);
    BTl[b]   = (ushort*)alloc((size_t)768 * dn[b] * 2);
    biasf[b] = (float*)alloc((size_t)dn[b] * 4);
  }
  int* offs[2]; int* cur[2]; int2* csr[2];
  const int* eis[2] = {ei1, ei2};
  const float* ews[2] = {ew1, ew2};
  for (int g = 0; g < 2; ++g) {
    offs[g] = (int*)alloc((size_t)(Nn + 1) * 4);
    cur[g]  = (int*)alloc((size_t)Nn * 4);
    csr[g]  = (int2*)alloc((size_t)E * 8);
  }
  // block-3 scratch aliased onto planes dead after block 2's GEMM:
  ushort* P   = XB;                        // [Nn,192] bf16 = 19.2 MB <= 25.6 MB (XB dead)
  float*  Z1f = (float*)z1;                // [Nn,64] f32 = 12.8 MB (z1 dead)
  float*  Z2f = (float*)z2;                // [Nn,64] f32 = 12.8 MB (z2 dead)

  // weight fusion (split bf16, transposed [dn][768])
  for (int b = 0; b < 3; ++b) {
    int totalq = 768 * (dn[b] >> 2);
    fuse_w_kernel<<<(totalq + 255) / 256, 256, 0, stream>>>(
        ibW[b][0], ibW[b][1], ibW[b][2], lnW[b], BTh[b], BTl[b], dmid[b], dn[b]);
    fuse_b_kernel<<<dn[b], 256, 0, stream>>>(
        ibB[b][0], ibB[b][1], ibB[b][2], lnW[b], lnb[b], biasf[b], dmid[b], dn[b]);
  }

  // CSR build (per graph, reused by all 3 blocks)
  for (int g = 0; g < 2; ++g) {
    hipMemsetAsync(cur[g], 0, (size_t)Nn * 4, stream);
    hist_kernel<<<(E + 255) / 256, 256, 0, stream>>>(eis[g], cur[g], E);
    scan_kernel<<<1, 1024, 0, stream>>>(cur[g], offs[g], cur[g], Nn);
    fill_kernel<<<(E + 255) / 256, 256, 0, stream>>>(eis[g], ews[g], cur[g], csr[g], E);
  }

  // x -> bf16
  size_t n4 = (size_t)Nn * 64;
  conv_bf16_kernel<<<(int)((n4 + 255) / 256), 256, 0, stream>>>(x, XA, n4);

  int aggGrid = (Nn + 3) / 4;
  int gg = (Nn + 63) / 64;

  // block 1: in XA(x) -> out XB
  agg_bf16_kernel<<<aggGrid, 256, 0, stream>>>(offs[0], csr[0], XA, z1, Nn);
  agg_bf16_kernel<<<aggGrid, 256, 0, stream>>>(offs[1], csr[1], XA, z2, Nn);
  gemm_mfma64_kernel<<<gg, 256, 0, stream>>>(
      XA, z1, z2, BTh[0], BTl[0], biasf[0], XB, Nn);

  // block 2: in XB -> out XA
  agg_bf16_kernel<<<aggGrid, 256, 0, stream>>>(offs[0], csr[0], XB, z1, Nn);
  agg_bf16_kernel<<<aggGrid, 256, 0, stream>>>(offs[1], csr[1], XB, z2, Nn);
  gemm_mfma64_kernel<<<gg, 256, 0, stream>>>(
      XB, z1, z2, BTh[1], BTl[1], biasf[1], XA, Nn);

  // block 3 (projection-first): p = XA @ [M0|M1|M2]; z_g = agg_g(p chunk); out = p0+z1+z2+bias
  gemm_proj_kernel<<<gg, 384, 0, stream>>>(XA, BTh[2], BTl[2], P, Nn);
  agg64_kernel<<<aggGrid, 256, 0, stream>>>(offs[0], csr[0], P, 64, Z1f, Nn);
  agg64_kernel<<<aggGrid, 256, 0, stream>>>(offs[1], csr[1], P, 128, Z2f, Nn);
  final_lsm_kernel<<<aggGrid, 256, 0, stream>>>(P, Z1f, Z2f, biasf[2], (float*)d_out, Nn);
}